// Round 13
// baseline (245.447 us; speedup 1.0000x reference)
//
#include <hip/hip_runtime.h>
#include <hip/hip_bf16.h>
#include <math.h>

// Problem constants (fixed by the reference's weight shapes):
#define DM     256   // d_model
#define NHEAD  8
#define HDIM   32
#define QPAD   112   // padded query rows per (b,h): 7 waves x 16 rows
#define NCHUNK 8     // L-chunks per (b,h) for flash parallelism
#define BM     64    // kv_gemm M-tile (tokens)
#define BN     256   // kv_gemm N-tile (output cols): ntile 0 = K, 1 = V
#define BK     32    // kv_gemm K-step
#define ALD    264   // As row stride in shorts (256 + 8 pad)
#define CQ     4     // combine queries per block (CQ=2 measured +20us, rd9)

typedef __attribute__((ext_vector_type(8))) short bf16x8;  // 8 bf16 (4 VGPRs)
typedef __attribute__((ext_vector_type(4))) short bf16x4;  // 8B packed store
typedef __attribute__((ext_vector_type(4))) float f32x4;   // 4 fp32 acc

__device__ __forceinline__ short f2bf(float f) {
  union { float f; unsigned u; } x; x.f = f;
  unsigned u = (x.u + 0x7fffu + ((x.u >> 16) & 1u)) >> 16;
  return (short)u;
}
__device__ __forceinline__ float bf2f(short s) {
  union { unsigned u; float f; } x; x.u = ((unsigned)(unsigned short)s) << 16;
  return x.f;
}
__device__ __forceinline__ bf16x8 bzero8() {
  bf16x8 v;
#pragma unroll
  for (int j = 0; j < 8; j++) v[j] = (short)0;
  return v;
}
__device__ __forceinline__ bf16x8 cvt8(const float* p) {
  float4 x0 = *(const float4*)p, x1 = *(const float4*)(p + 4);
  bf16x8 v;
  v[0] = f2bf(x0.x); v[1] = f2bf(x0.y); v[2] = f2bf(x0.z); v[3] = f2bf(x0.w);
  v[4] = f2bf(x1.x); v[5] = f2bf(x1.y); v[6] = f2bf(x1.z); v[7] = f2bf(x1.w);
  return v;
}
__device__ __forceinline__ bf16x8 cvt8s(const float* p, float s) {
  float4 x0 = *(const float4*)p, x1 = *(const float4*)(p + 4);
  bf16x8 v;
  v[0] = f2bf(x0.x * s); v[1] = f2bf(x0.y * s);
  v[2] = f2bf(x0.z * s); v[3] = f2bf(x0.w * s);
  v[4] = f2bf(x1.x * s); v[5] = f2bf(x1.y * s);
  v[6] = f2bf(x1.z * s); v[7] = f2bf(x1.w * s);
  return v;
}

// ---------------------------------------------------------------------------
// Kernel 0: weight convert.  Wkvq[n][k] bf16 (768 rows):
//   n <  256: Wk row n
//   n < 512 : Wv row n-256
//   n < 768 : Wq row n-512, PRE-SCALED by 1/sqrt(32) (folds the q scale)
// ---------------------------------------------------------------------------
__global__ __launch_bounds__(256) void wconv_kernel(
    const float* __restrict__ Wk, const float* __restrict__ Wv,
    const float* __restrict__ Wq, short* __restrict__ Wkvq) {
  int idx = blockIdx.x * 256 + threadIdx.x;
  int e0 = idx * 8;
  const float* p;
  float s = 1.f;
  if (e0 < DM * DM) {
    p = Wk + e0;
  } else if (e0 < 2 * DM * DM) {
    p = Wv + (e0 - DM * DM);
  } else {
    p = Wq + (e0 - 2 * DM * DM);
    s = 0.17677669529663687f;  // 1/sqrt(32)
  }
  *(bf16x8*)(Wkvq + e0) = cvt8s(p, s);
}

// ---------------------------------------------------------------------------
// Kernel 2: fused projection GEMM, 64x256 tiles, 4 waves (1x4 over N).
//   blocks [0, qtiles): Q projection as MFMA (placed FIRST so they fold into
//     the first scheduling round instead of forming a serialized tail).
//   blocks [qtiles, qtiles+kvb): KV projection (measured-best config): stage
//     ALL of A (64x256 bf16 = 33.8 KB) into LDS once, barrier-free K-loop,
//     B frags from L2-resident bf16 Wkvq straight into MFMA layout.
//     K/V-paired grid on (bid - qtiles): pairs share idx%8 (same XCD), 8 IDs
//     apart -> src re-read is an L2 hit. K: SWAPPED mfma (C^T); V: normal.
// ---------------------------------------------------------------------------
__global__ __launch_bounds__(256) void kv_gemm_kernel(
    const float* __restrict__ src, const float* __restrict__ query,
    const short* __restrict__ Wkvq, const float* __restrict__ bq,
    const float* __restrict__ bk, const float* __restrict__ bv,
    const int* __restrict__ offs, short* __restrict__ Qw,
    short* __restrict__ Kw, short* __restrict__ Vw, int T, int Bn, int NQ,
    int Mtiles, int qtiles) {
  int bid = blockIdx.x;
  int tid = threadIdx.x;
  int wave = tid >> 6, lane = tid & 63;
  int l15 = lane & 15, quad = lane >> 4;

  bool isQ = (bid < qtiles);
  const float* Asrc;
  int Arows, t0, n0;
  bool swapped;
  bool isK = false;
  if (isQ) {
    t0 = bid * BM;
    Asrc = query;
    Arows = Bn * NQ;
    n0 = 2 * DM;       // Wq rows of Wkvq
    swapped = true;    // C^T epilogue
  } else {
    int kvbid = bid - qtiles;
    int mtile = (kvbid >> 4) * 8 + (kvbid & 7);
    int ntile = (kvbid >> 3) & 1;
    if (mtile >= Mtiles) return;
    t0 = mtile * BM;
    n0 = ntile * BN;   // 0 => K cols, 256 => V cols
    isK = (ntile == 0);
    swapped = isK;
    Asrc = src;
    Arows = T;
  }

  __shared__ __align__(16) short As[BM * ALD];  // full-K A tile, bf16

  f32x4 acc[4][4];
#pragma unroll
  for (int i = 0; i < 4; i++)
#pragma unroll
    for (int j = 0; j < 4; j++) acc[i][j] = (f32x4){0.f, 0.f, 0.f, 0.f};

  // ---- prologue: stage all of A (fp32 -> bf16), one barrier total ----
  {
    int arow = tid >> 2, ac4 = tid & 3;
    int atok = t0 + arow;
    if (atok >= Arows) atok = Arows - 1;
    const float* arp = Asrc + (size_t)atok * DM;
#pragma unroll
    for (int r = 0; r < 4; r++) {
      int c0 = r * 64 + ac4 * 16;
      const float* p = arp + c0;
      bf16x8 v0 = cvt8(p);
      bf16x8 v1 = cvt8(p + 8);
      *(bf16x8*)&As[arow * ALD + c0]     = v0;
      *(bf16x8*)&As[arow * ALD + c0 + 8] = v1;
    }
  }
  __syncthreads();

  // ---- barrier-free K-loop: B from bf16 Wkvq (L2), A from LDS ----
  const short* bptr = Wkvq + (size_t)(n0 + wave * 64 + l15) * DM + quad * 8;
#pragma unroll
  for (int kk = 0; kk < DM; kk += BK) {
    bf16x8 bf_[4];
#pragma unroll
    for (int nt = 0; nt < 4; nt++)
      bf_[nt] = *(const bf16x8*)(bptr + (size_t)nt * 16 * DM + kk);
    bf16x8 af[4];
#pragma unroll
    for (int mt = 0; mt < 4; mt++)
      af[mt] = *(const bf16x8*)&As[(mt * 16 + l15) * ALD + kk + quad * 8];
    if (swapped) {
#pragma unroll
      for (int mt = 0; mt < 4; mt++)
#pragma unroll
        for (int nt = 0; nt < 4; nt++)
          acc[mt][nt] = __builtin_amdgcn_mfma_f32_16x16x32_bf16(
              bf_[nt], af[mt], acc[mt][nt], 0, 0, 0);  // C^T
    } else {
#pragma unroll
      for (int mt = 0; mt < 4; mt++)
#pragma unroll
        for (int nt = 0; nt < 4; nt++)
          acc[mt][nt] = __builtin_amdgcn_mfma_f32_16x16x32_bf16(
              af[mt], bf_[nt], acc[mt][nt], 0, 0, 0);
    }
  }

  if (isQ) {
    // C^T: lane l15 = query row (within 16), reg r = hd offset quad*4+r.
    const float scale = 0.17677669529663687f;
    float bq4[4][4];
    int hQ[4], hdQ[4];
#pragma unroll
    for (int nt = 0; nt < 4; nt++) {
      int nbq = wave * 64 + nt * 16 + quad * 4;
      float4 b4 = *(const float4*)(bq + nbq);
      bq4[nt][0] = b4.x * scale; bq4[nt][1] = b4.y * scale;
      bq4[nt][2] = b4.z * scale; bq4[nt][3] = b4.w * scale;
      hQ[nt] = nbq >> 5;
      hdQ[nt] = nbq & 31;
    }
#pragma unroll
    for (int mt = 0; mt < 4; mt++) {
      int row = t0 + mt * 16 + l15;
      if (row >= Arows) continue;
      int b = row / NQ;
      int q = row - b * NQ;
#pragma unroll
      for (int nt = 0; nt < 4; nt++) {
        bf16x4 p;
#pragma unroll
        for (int r = 0; r < 4; r++) p[r] = f2bf(acc[mt][nt][r] + bq4[nt][r]);
        *(bf16x4*)&Qw[(((size_t)b * NHEAD + hQ[nt]) * QPAD + q) * HDIM +
                      hdQ[nt]] = p;
      }
    }
  } else if (isK) {
    const float* bias = bk;
    // C^T: lane l15 = token (within 16), reg r = hd offset quad*4+r.
    float bk4[4][4];
    int hK[4], hdK[4];
#pragma unroll
    for (int nt = 0; nt < 4; nt++) {
      int nbq = wave * 64 + nt * 16 + quad * 4;
      float4 b4 = *(const float4*)(bias + nbq);
      bk4[nt][0] = b4.x; bk4[nt][1] = b4.y; bk4[nt][2] = b4.z; bk4[nt][3] = b4.w;
      hK[nt] = nbq >> 5;
      hdK[nt] = nbq & 31;
    }
    int bcur = 0;
#pragma unroll
    for (int mt = 0; mt < 4; mt++) {
      int tok = t0 + mt * 16 + l15;
      if (tok >= T) continue;
      while (bcur + 1 < Bn && offs[bcur + 1] <= tok) bcur++;
      int off = offs[bcur], len = offs[bcur + 1] - off;
      int l = tok - off;
      size_t bb = (size_t)off * DM;
#pragma unroll
      for (int nt = 0; nt < 4; nt++) {
        bf16x4 p;
#pragma unroll
        for (int r = 0; r < 4; r++) p[r] = f2bf(acc[mt][nt][r] + bk4[nt][r]);
        *(bf16x4*)&Kw[bb + (size_t)hK[nt] * len * HDIM + (size_t)l * HDIM +
                      hdK[nt]] = p;
      }
    }
  } else {
    const float* bias = bv;
    // Normal C: lane l15 = hd (within 16), reg r = token offset quad*4+r.
    float bV[4];
    int hV[4], hdV[4];
#pragma unroll
    for (int nt = 0; nt < 4; nt++) {
      int nb = wave * 64 + nt * 16 + l15;
      bV[nt] = bias[nb];
      hV[nt] = nb >> 5;
      hdV[nt] = nb & 31;
    }
    int bcur = 0;
#pragma unroll
    for (int mt = 0; mt < 4; mt++) {
      int tb = t0 + mt * 16 + quad * 4;
      if (tb >= T) continue;
      while (bcur + 1 < Bn && offs[bcur + 1] <= tb) bcur++;
      int off = offs[bcur], len = offs[bcur + 1] - off;
      size_t bb = (size_t)off * DM;
      bool span = (tb + 3 < offs[bcur + 1]) && (tb + 3 < T);
      if (span) {
        int l = tb - off;
#pragma unroll
        for (int nt = 0; nt < 4; nt++) {
          size_t idx =
              bb + (size_t)hV[nt] * len * HDIM + (size_t)hdV[nt] * len + l;
          bf16x4 p;
#pragma unroll
          for (int r = 0; r < 4; r++) p[r] = f2bf(acc[mt][nt][r] + bV[nt]);
          if ((idx & 3) == 0) {
            *(bf16x4*)&Vw[idx] = p;
          } else {
#pragma unroll
            for (int r = 0; r < 4; r++) Vw[idx + r] = p[r];
          }
        }
      } else {
        int bc2 = bcur;
#pragma unroll
        for (int r = 0; r < 4; r++) {
          int tok = tb + r;
          if (tok >= T) continue;
          while (bc2 + 1 < Bn && offs[bc2 + 1] <= tok) bc2++;
          int off2 = offs[bc2], len2 = offs[bc2 + 1] - off2;
          int l = tok - off2;
          size_t bb2 = (size_t)off2 * DM;
#pragma unroll
          for (int nt = 0; nt < 4; nt++)
            Vw[bb2 + (size_t)hV[nt] * len2 * HDIM + (size_t)hdV[nt] * len2 +
               l] = f2bf(acc[mt][nt][r] + bV[nt]);
        }
      }
    }
  }
}

// ---------------------------------------------------------------------------
// Kernel 3: flash attention per (b, h, chunk). 7 waves x 16 query rows.
// 64-key iterations (4 QK tiles/step). Round-11 config (measured best):
// online max (4-shfl cascade) + DEFERRED row-sum (per-lane partial, one
// all-reduce after the loop). Round-12's static-max (zero shfls) measured
// SLOWER — the max cascade overlaps with loads and is off the critical path.
// Writes unnormalized O (QPAD x 32, bf16) + per-row (m, l) fp32.
// ---------------------------------------------------------------------------
__global__ __launch_bounds__(448) void attn_kernel(
    const short* __restrict__ Qw, const short* __restrict__ Kw,
    const short* __restrict__ Vw, const int* __restrict__ offs,
    short* __restrict__ Ops, float* __restrict__ Ml, int Bn) {
  int c  = blockIdx.x % NCHUNK;
  int bh = blockIdx.x / NCHUNK;
  int h = bh % NHEAD, b = bh / NHEAD;
  int wave = threadIdx.x >> 6, lane = threadIdx.x & 63;
  int l15 = lane & 15, quad = lane >> 4;

  int off = offs[b], len = offs[b + 1] - off;
  int cl = ((len + NCHUNK * 32 - 1) / (NCHUNK * 32)) * 32;
  int kstart = c * cl;
  int kend   = min(kstart + cl, len);

  const short* Kh = Kw + (size_t)off * DM + (size_t)h * len * HDIM;
  const short* Vh = Vw + (size_t)off * DM + (size_t)h * len * HDIM;

  int row16 = wave * 16 + l15;
  bf16x8 aq = *(const bf16x8*)(
      Qw + (((size_t)b * NHEAD + h) * QPAD + row16) * HDIM + quad * 8);

  f32x4 o[2];
#pragma unroll
  for (int j = 0; j < 2; j++) o[j] = (f32x4){0.f, 0.f, 0.f, 0.f};
  float mrun[4], lrun[4];  // lrun = PER-LANE partial sum (reduced at end)
#pragma unroll
  for (int r = 0; r < 4; r++) { mrun[r] = -1e30f; lrun[r] = 0.f; }

  __shared__ __align__(16) short plds[7][16][72];  // wave-private P transpose

  for (int kb = kstart; kb < kend; kb += 64) {
    bool valid[4];
    bf16x8 bk_[4];
#pragma unroll
    for (int nt = 0; nt < 4; nt++) {
      int key = kb + nt * 16 + l15;
      valid[nt] = key < kend;
      bk_[nt] = valid[nt]
                    ? *(const bf16x8*)(Kh + (size_t)key * HDIM + quad * 8)
                    : bzero8();
    }
    f32x4 zero = {0.f, 0.f, 0.f, 0.f};
    f32x4 s[4];
#pragma unroll
    for (int nt = 0; nt < 4; nt++)
      s[nt] = __builtin_amdgcn_mfma_f32_16x16x32_bf16(aq, bk_[nt], zero, 0, 0, 0);
#pragma unroll
    for (int r = 0; r < 4; r++) {
      float v0 = valid[0] ? s[0][r] : -1e30f;
      float v1 = valid[1] ? s[1][r] : -1e30f;
      float v2 = valid[2] ? s[2][r] : -1e30f;
      float v3 = valid[3] ? s[3][r] : -1e30f;
      float t = fmaxf(fmaxf(v0, v1), fmaxf(v2, v3));
      t = fmaxf(t, __shfl_xor(t, 1, 16));
      t = fmaxf(t, __shfl_xor(t, 2, 16));
      t = fmaxf(t, __shfl_xor(t, 4, 16));
      t = fmaxf(t, __shfl_xor(t, 8, 16));
      float mn = fmaxf(mrun[r], t);
      float al = __expf(mrun[r] - mn);      // row-uniform (mn all-reduced)
      float p0 = valid[0] ? __expf(v0 - mn) : 0.f;
      float p1 = valid[1] ? __expf(v1 - mn) : 0.f;
      float p2 = valid[2] ? __expf(v2 - mn) : 0.f;
      float p3 = valid[3] ? __expf(v3 - mn) : 0.f;
      lrun[r] = al * lrun[r] + ((p0 + p1) + (p2 + p3));  // per-lane partial
      mrun[r] = mn;
      o[0][r] *= al;
      o[1][r] *= al;
      plds[wave][quad * 4 + r][l15]      = f2bf(p0);
      plds[wave][quad * 4 + r][16 + l15] = f2bf(p1);
      plds[wave][quad * 4 + r][32 + l15] = f2bf(p2);
      plds[wave][quad * 4 + r][48 + l15] = f2bf(p3);
    }
    bf16x8 pa0 = *(const bf16x8*)&plds[wave][l15][quad * 8];
    bf16x8 pa1 = *(const bf16x8*)&plds[wave][l15][32 + quad * 8];
    bf16x8 bv_[2][2];
#pragma unroll
    for (int half = 0; half < 2; half++) {
#pragma unroll
      for (int ht = 0; ht < 2; ht++) {
        int hd = ht * 16 + l15;
        int k0 = kb + half * 32 + quad * 8;
        const short* p = Vh + (size_t)hd * len + k0;
        if (k0 + 7 < len) {
          bv_[half][ht] = *(const bf16x8*)p;
        } else {
          bf16x8 v;
#pragma unroll
          for (int j = 0; j < 8; j++) v[j] = (k0 + j < len) ? p[j] : (short)0;
          bv_[half][ht] = v;
        }
      }
    }
#pragma unroll
    for (int ht = 0; ht < 2; ht++) {
      o[ht] = __builtin_amdgcn_mfma_f32_16x16x32_bf16(pa0, bv_[0][ht], o[ht],
                                                      0, 0, 0);
      o[ht] = __builtin_amdgcn_mfma_f32_16x16x32_bf16(pa1, bv_[1][ht], o[ht],
                                                      0, 0, 0);
    }
  }

  // final row-sum all-reduce (hoisted out of the loop), once per block
#pragma unroll
  for (int r = 0; r < 4; r++) {
    lrun[r] += __shfl_xor(lrun[r], 1, 16);
    lrun[r] += __shfl_xor(lrun[r], 2, 16);
    lrun[r] += __shfl_xor(lrun[r], 4, 16);
    lrun[r] += __shfl_xor(lrun[r], 8, 16);
  }

#pragma unroll
  for (int r = 0; r < 4; r++) {
    int row = wave * 16 + quad * 4 + r;
    size_t base = (((size_t)c * Bn + b) * NHEAD + h) * QPAD + row;
#pragma unroll
    for (int ht = 0; ht < 2; ht++)
      Ops[base * HDIM + ht * 16 + l15] = f2bf(o[ht][r]);
    if (l15 == 0) {
      Ml[base * 2]     = mrun[r];
      Ml[base * 2 + 1] = lrun[r];
    }
  }
}

// ---------------------------------------------------------------------------
// Kernel 4: chunk combine + out-projection + residual. CQ=4 queries/block
// (measured best rd7/rd8; CQ=2 regressed ~20 us in rd9).
// LDS-staged vectorized Ops/Ml loads.
// ---------------------------------------------------------------------------
__global__ __launch_bounds__(256) void combine_kernel(
    const short* __restrict__ Ops, const float* __restrict__ Ml,
    const float* __restrict__ query, const float* __restrict__ Wo,
    const float* __restrict__ bo, float* __restrict__ out, int Bn, int NQ) {
  int bpb = (NQ + CQ - 1) / CQ;
  int b  = blockIdx.x / bpb;
  int q0 = (blockIdx.x % bpb) * CQ;
  int tid = threadIdx.x;

  __shared__ __align__(16) short opsl[CQ][NCHUNK][DM];  // 16 KB
  __shared__ float mll[NCHUNK][NHEAD][CQ][2];           // 2 KB
  __shared__ __align__(16) float ctx[CQ * DM];          // 4 KB

  for (int t = tid; t < CQ * NCHUNK * (DM / 8); t += 256) {
    int q   = t / (NCHUNK * 32);
    int rem = t % (NCHUNK * 32);
    int c   = rem / 32;
    int v   = rem % 32;           // 8-elem chunk within 256 = h*32+hd0
    int h   = v >> 2;
    int hd0 = (v & 3) * 8;
    int qq = q0 + q;
    if (qq >= NQ) qq = NQ - 1;
    size_t base = (((size_t)c * Bn + b) * NHEAD + h) * QPAD + qq;
    *(bf16x8*)&opsl[q][c][v * 8] = *(const bf16x8*)&Ops[base * HDIM + hd0];
  }
  for (int t = tid; t < CQ * NCHUNK * NHEAD; t += 256) {
    int q   = t / (NCHUNK * NHEAD);
    int rem = t % (NCHUNK * NHEAD);
    int c   = rem / NHEAD;
    int h   = rem % NHEAD;
    int qq = q0 + q;
    if (qq >= NQ) qq = NQ - 1;
    size_t base = (((size_t)c * Bn + b) * NHEAD + h) * QPAD + qq;
    mll[c][h][q][0] = Ml[base * 2];
    mll[c][h][q][1] = Ml[base * 2 + 1];
  }
  __syncthreads();

  int d = tid, h = d >> 5;
#pragma unroll
  for (int qi = 0; qi < CQ; qi++) {
    float M = -1e30f;
#pragma unroll
    for (int c = 0; c < NCHUNK; c++) M = fmaxf(M, mll[c][h][qi][0]);
    float L = 0.f, acc = 0.f;
#pragma unroll
    for (int c = 0; c < NCHUNK; c++) {
      float w = __expf(mll[c][h][qi][0] - M);
      L += mll[c][h][qi][1] * w;
      acc += w * bf2f(opsl[qi][c][d]);
    }
    ctx[qi * DM + d] = (L > 0.f) ? acc / L : 0.f;
  }
  __syncthreads();

  const float* wrow = Wo + (size_t)d * DM;
  float acc[CQ];
  float bias = bo[d];
#pragma unroll
  for (int qi = 0; qi < CQ; qi++) acc[qi] = bias;
  for (int k = 0; k < DM; k += 4) {
    float4 w = *(const float4*)(wrow + k);
#pragma unroll
    for (int qi = 0; qi < CQ; qi++) {
      float4 x = *(const float4*)&ctx[qi * DM + k];
      acc[qi] += x.x * w.x + x.y * w.y + x.z * w.z + x.w * w.w;
    }
  }
#pragma unroll
  for (int qi = 0; qi < CQ; qi++) {
    int q = q0 + qi;
    if (q < NQ)
      out[((size_t)b * NQ + q) * DM + d] =
          acc[qi] + query[((size_t)b * NQ + q) * DM + d];
  }
}

// ---------------------------------------------------------------------------
extern "C" void kernel_launch(void* const* d_in, const int* in_sizes, int n_in,
                              void* d_out, int out_size, void* d_ws,
                              size_t ws_size, hipStream_t stream) {
  const float* src   = (const float*)d_in[0];
  const float* query = (const float*)d_in[1];
  const int*   offs  = (const int*)d_in[2];
  const float* Wq = (const float*)d_in[3];
  const float* bq = (const float*)d_in[4];
  const float* Wk = (const float*)d_in[5];
  const float* bk = (const float*)d_in[6];
  const float* Wv = (const float*)d_in[7];
  const float* bv = (const float*)d_in[8];
  const float* Wo = (const float*)d_in[9];
  const float* bo = (const float*)d_in[10];
  float* out = (float*)d_out;

  int T  = in_sizes[0] / DM;        // total tokens (65536)
  int Bn = in_sizes[2] - 1;         // batch size (16)
  int NQ = in_sizes[1] / (Bn * DM); // queries per sample (100)

  // Workspace layout (~77 MB):
  char* w = (char*)d_ws;
  size_t qsz = (size_t)Bn * NHEAD * QPAD * HDIM * 2;            // 0.92 MB
  size_t ksz = (size_t)T * DM * 2;                              // 33.5 MB
  size_t osz = (size_t)NCHUNK * Bn * NHEAD * QPAD * HDIM * 2;   // 7.3 MB (bf16)
  size_t msz = (size_t)NCHUNK * Bn * NHEAD * QPAD * 2 * 4;      // 0.92 MB
  short* Qw  = (short*)w;
  short* Kw  = (short*)(w + qsz);
  short* Vw  = (short*)(w + qsz + ksz);
  short* Ops = (short*)(w + qsz + 2 * ksz);
  float* Mlp = (float*)(w + qsz + 2 * ksz + osz);
  short* Wkvq = (short*)(w + qsz + 2 * ksz + osz + msz);        // 0.39 MB

  int Mtiles = (T + BM - 1) / BM;
  int groups = (Mtiles + 7) / 8;
  int kvb = groups * 16;                   // kv blocks (2048)
  int qtiles = (Bn * NQ + BM - 1) / BM;    // q-proj MFMA blocks (25), FIRST

  wconv_kernel<<<(3 * DM * DM) / (256 * 8), 256, 0, stream>>>(Wk, Wv, Wq,
                                                              Wkvq);
  kv_gemm_kernel<<<qtiles + kvb, 256, 0, stream>>>(
      src, query, Wkvq, bq, bk, bv, offs, Qw, Kw, Vw, T, Bn, NQ, Mtiles,
      qtiles);
  attn_kernel<<<Bn * NHEAD * NCHUNK, 448, 0, stream>>>(Qw, Kw, Vw, offs, Ops,
                                                       Mlp, Bn);
  combine_kernel<<<Bn * ((NQ + CQ - 1) / CQ), 256, 0, stream>>>(
      Ops, Mlp, query, Wo, bo, out, Bn, NQ);
}

// Round 14
// 231.780 us; speedup vs baseline: 1.0590x; 1.0590x over previous
//
#include <hip/hip_runtime.h>
#include <hip/hip_bf16.h>
#include <math.h>

// Problem constants (fixed by the reference's weight shapes):
#define DM     256   // d_model
#define NHEAD  8
#define HDIM   32
#define QPAD   112   // padded query rows per (b,h): 7 waves x 16 rows
#define NCHUNK 8     // L-chunks per (b,h) for flash parallelism
#define BM     64    // kv_gemm M-tile (tokens)
#define BN     256   // kv_gemm N-tile (output cols): ntile 0 = K, 1 = V
#define BK     32    // kv_gemm K-step
#define ALD    264   // As row stride in shorts (256 + 8 pad)
#define CQ     4     // combine queries per block (CQ=2 measured +20us, rd9)

typedef __attribute__((ext_vector_type(8))) short bf16x8;  // 8 bf16 (4 VGPRs)
typedef __attribute__((ext_vector_type(4))) short bf16x4;  // 8B packed store
typedef __attribute__((ext_vector_type(4))) float f32x4;   // 4 fp32 acc

__device__ __forceinline__ short f2bf(float f) {
  union { float f; unsigned u; } x; x.f = f;
  unsigned u = (x.u + 0x7fffu + ((x.u >> 16) & 1u)) >> 16;
  return (short)u;
}
__device__ __forceinline__ float bf2f(short s) {
  union { unsigned u; float f; } x; x.u = ((unsigned)(unsigned short)s) << 16;
  return x.f;
}
__device__ __forceinline__ bf16x8 bzero8() {
  bf16x8 v;
#pragma unroll
  for (int j = 0; j < 8; j++) v[j] = (short)0;
  return v;
}
__device__ __forceinline__ bf16x8 cvt8(const float* p) {
  float4 x0 = *(const float4*)p, x1 = *(const float4*)(p + 4);
  bf16x8 v;
  v[0] = f2bf(x0.x); v[1] = f2bf(x0.y); v[2] = f2bf(x0.z); v[3] = f2bf(x0.w);
  v[4] = f2bf(x1.x); v[5] = f2bf(x1.y); v[6] = f2bf(x1.z); v[7] = f2bf(x1.w);
  return v;
}
__device__ __forceinline__ bf16x8 cvt8s(const float* p, float s) {
  float4 x0 = *(const float4*)p, x1 = *(const float4*)(p + 4);
  bf16x8 v;
  v[0] = f2bf(x0.x * s); v[1] = f2bf(x0.y * s);
  v[2] = f2bf(x0.z * s); v[3] = f2bf(x0.w * s);
  v[4] = f2bf(x1.x * s); v[5] = f2bf(x1.y * s);
  v[6] = f2bf(x1.z * s); v[7] = f2bf(x1.w * s);
  return v;
}

// ---------------------------------------------------------------------------
// Kernel 0: weight convert.  Wkvq[n][k] bf16 (768 rows):
//   n <  256: Wk row n
//   n < 512 : Wv row n-256
//   n < 768 : Wq row n-512, PRE-SCALED by 1/sqrt(32) (folds the q scale)
// ---------------------------------------------------------------------------
__global__ __launch_bounds__(256) void wconv_kernel(
    const float* __restrict__ Wk, const float* __restrict__ Wv,
    const float* __restrict__ Wq, short* __restrict__ Wkvq) {
  int idx = blockIdx.x * 256 + threadIdx.x;
  int e0 = idx * 8;
  const float* p;
  float s = 1.f;
  if (e0 < DM * DM) {
    p = Wk + e0;
  } else if (e0 < 2 * DM * DM) {
    p = Wv + (e0 - DM * DM);
  } else {
    p = Wq + (e0 - 2 * DM * DM);
    s = 0.17677669529663687f;  // 1/sqrt(32)
  }
  *(bf16x8*)(Wkvq + e0) = cvt8s(p, s);
}

// ---------------------------------------------------------------------------
// Kernel 2: fused projection GEMM, 64x256 tiles, 4 waves (1x4 over N).
//   blocks [0, kvb): KV projection (measured-best config): stage ALL of A
//     (64x256 bf16 = 33.8 KB) into LDS once, barrier-free K-loop, B frags
//     from L2-resident bf16 Wkvq straight into MFMA layout. K/V-paired grid
//     (same XCD, 8 IDs apart -> src L2 hit). K: SWAPPED mfma (C^T); V:
//     normal.
//   blocks [kvb, kvb+25): Q projection as MFMA.
// NOTE (rd13 lesson): keep this exact code layout — reordering the Q/KV
// branch pushed VGPR 120->132, crossing the 128-VGPR occupancy cliff
// (3->2 blocks/CU) and cost +14 us on this latency-bound kernel.
// ---------------------------------------------------------------------------
__global__ __launch_bounds__(256) void kv_gemm_kernel(
    const float* __restrict__ src, const float* __restrict__ query,
    const short* __restrict__ Wkvq, const float* __restrict__ bq,
    const float* __restrict__ bk, const float* __restrict__ bv,
    const int* __restrict__ offs, short* __restrict__ Qw,
    short* __restrict__ Kw, short* __restrict__ Vw, int T, int Bn, int NQ,
    int Mtiles, int kvb) {
  int bid = blockIdx.x;
  int tid = threadIdx.x;
  int wave = tid >> 6, lane = tid & 63;
  int l15 = lane & 15, quad = lane >> 4;

  bool isQ = (bid >= kvb);
  const float* Asrc;
  int Arows, t0, n0;
  bool swapped;
  bool isK = false;
  if (isQ) {
    int qt = bid - kvb;
    t0 = qt * BM;
    Asrc = query;
    Arows = Bn * NQ;
    n0 = 2 * DM;       // Wq rows of Wkvq
    swapped = true;    // C^T epilogue
  } else {
    int mtile = (bid >> 4) * 8 + (bid & 7);
    int ntile = (bid >> 3) & 1;
    if (mtile >= Mtiles) return;
    t0 = mtile * BM;
    n0 = ntile * BN;   // 0 => K cols, 256 => V cols
    isK = (ntile == 0);
    swapped = isK;
    Asrc = src;
    Arows = T;
  }

  __shared__ __align__(16) short As[BM * ALD];  // full-K A tile, bf16

  f32x4 acc[4][4];
#pragma unroll
  for (int i = 0; i < 4; i++)
#pragma unroll
    for (int j = 0; j < 4; j++) acc[i][j] = (f32x4){0.f, 0.f, 0.f, 0.f};

  // ---- prologue: stage all of A (fp32 -> bf16), one barrier total ----
  {
    int arow = tid >> 2, ac4 = tid & 3;
    int atok = t0 + arow;
    if (atok >= Arows) atok = Arows - 1;
    const float* arp = Asrc + (size_t)atok * DM;
#pragma unroll
    for (int r = 0; r < 4; r++) {
      int c0 = r * 64 + ac4 * 16;
      const float* p = arp + c0;
      bf16x8 v0 = cvt8(p);
      bf16x8 v1 = cvt8(p + 8);
      *(bf16x8*)&As[arow * ALD + c0]     = v0;
      *(bf16x8*)&As[arow * ALD + c0 + 8] = v1;
    }
  }
  __syncthreads();

  // ---- barrier-free K-loop: B from bf16 Wkvq (L2), A from LDS ----
  const short* bptr = Wkvq + (size_t)(n0 + wave * 64 + l15) * DM + quad * 8;
#pragma unroll
  for (int kk = 0; kk < DM; kk += BK) {
    bf16x8 bf_[4];
#pragma unroll
    for (int nt = 0; nt < 4; nt++)
      bf_[nt] = *(const bf16x8*)(bptr + (size_t)nt * 16 * DM + kk);
    bf16x8 af[4];
#pragma unroll
    for (int mt = 0; mt < 4; mt++)
      af[mt] = *(const bf16x8*)&As[(mt * 16 + l15) * ALD + kk + quad * 8];
    if (swapped) {
#pragma unroll
      for (int mt = 0; mt < 4; mt++)
#pragma unroll
        for (int nt = 0; nt < 4; nt++)
          acc[mt][nt] = __builtin_amdgcn_mfma_f32_16x16x32_bf16(
              bf_[nt], af[mt], acc[mt][nt], 0, 0, 0);  // C^T
    } else {
#pragma unroll
      for (int mt = 0; mt < 4; mt++)
#pragma unroll
        for (int nt = 0; nt < 4; nt++)
          acc[mt][nt] = __builtin_amdgcn_mfma_f32_16x16x32_bf16(
              af[mt], bf_[nt], acc[mt][nt], 0, 0, 0);
    }
  }

  if (isQ) {
    // C^T: lane l15 = query row (within 16), reg r = hd offset quad*4+r.
    const float scale = 0.17677669529663687f;
    float bq4[4][4];
    int hQ[4], hdQ[4];
#pragma unroll
    for (int nt = 0; nt < 4; nt++) {
      int nbq = wave * 64 + nt * 16 + quad * 4;
      float4 b4 = *(const float4*)(bq + nbq);
      bq4[nt][0] = b4.x * scale; bq4[nt][1] = b4.y * scale;
      bq4[nt][2] = b4.z * scale; bq4[nt][3] = b4.w * scale;
      hQ[nt] = nbq >> 5;
      hdQ[nt] = nbq & 31;
    }
#pragma unroll
    for (int mt = 0; mt < 4; mt++) {
      int row = t0 + mt * 16 + l15;
      if (row >= Arows) continue;
      int b = row / NQ;
      int q = row - b * NQ;
#pragma unroll
      for (int nt = 0; nt < 4; nt++) {
        bf16x4 p;
#pragma unroll
        for (int r = 0; r < 4; r++) p[r] = f2bf(acc[mt][nt][r] + bq4[nt][r]);
        *(bf16x4*)&Qw[(((size_t)b * NHEAD + hQ[nt]) * QPAD + q) * HDIM +
                      hdQ[nt]] = p;
      }
    }
  } else if (isK) {
    const float* bias = bk;
    // C^T: lane l15 = token (within 16), reg r = hd offset quad*4+r.
    float bk4[4][4];
    int hK[4], hdK[4];
#pragma unroll
    for (int nt = 0; nt < 4; nt++) {
      int nbq = wave * 64 + nt * 16 + quad * 4;
      float4 b4 = *(const float4*)(bias + nbq);
      bk4[nt][0] = b4.x; bk4[nt][1] = b4.y; bk4[nt][2] = b4.z; bk4[nt][3] = b4.w;
      hK[nt] = nbq >> 5;
      hdK[nt] = nbq & 31;
    }
    int bcur = 0;
#pragma unroll
    for (int mt = 0; mt < 4; mt++) {
      int tok = t0 + mt * 16 + l15;
      if (tok >= T) continue;
      while (bcur + 1 < Bn && offs[bcur + 1] <= tok) bcur++;
      int off = offs[bcur], len = offs[bcur + 1] - off;
      int l = tok - off;
      size_t bb = (size_t)off * DM;
#pragma unroll
      for (int nt = 0; nt < 4; nt++) {
        bf16x4 p;
#pragma unroll
        for (int r = 0; r < 4; r++) p[r] = f2bf(acc[mt][nt][r] + bk4[nt][r]);
        *(bf16x4*)&Kw[bb + (size_t)hK[nt] * len * HDIM + (size_t)l * HDIM +
                      hdK[nt]] = p;
      }
    }
  } else {
    const float* bias = bv;
    // Normal C: lane l15 = hd (within 16), reg r = token offset quad*4+r.
    float bV[4];
    int hV[4], hdV[4];
#pragma unroll
    for (int nt = 0; nt < 4; nt++) {
      int nb = wave * 64 + nt * 16 + l15;
      bV[nt] = bias[nb];
      hV[nt] = nb >> 5;
      hdV[nt] = nb & 31;
    }
    int bcur = 0;
#pragma unroll
    for (int mt = 0; mt < 4; mt++) {
      int tb = t0 + mt * 16 + quad * 4;
      if (tb >= T) continue;
      while (bcur + 1 < Bn && offs[bcur + 1] <= tb) bcur++;
      int off = offs[bcur], len = offs[bcur + 1] - off;
      size_t bb = (size_t)off * DM;
      bool span = (tb + 3 < offs[bcur + 1]) && (tb + 3 < T);
      if (span) {
        int l = tb - off;
#pragma unroll
        for (int nt = 0; nt < 4; nt++) {
          size_t idx =
              bb + (size_t)hV[nt] * len * HDIM + (size_t)hdV[nt] * len + l;
          bf16x4 p;
#pragma unroll
          for (int r = 0; r < 4; r++) p[r] = f2bf(acc[mt][nt][r] + bV[nt]);
          if ((idx & 3) == 0) {
            *(bf16x4*)&Vw[idx] = p;
          } else {
#pragma unroll
            for (int r = 0; r < 4; r++) Vw[idx + r] = p[r];
          }
        }
      } else {
        int bc2 = bcur;
#pragma unroll
        for (int r = 0; r < 4; r++) {
          int tok = tb + r;
          if (tok >= T) continue;
          while (bc2 + 1 < Bn && offs[bc2 + 1] <= tok) bc2++;
          int off2 = offs[bc2], len2 = offs[bc2 + 1] - off2;
          int l = tok - off2;
          size_t bb2 = (size_t)off2 * DM;
#pragma unroll
          for (int nt = 0; nt < 4; nt++)
            Vw[bb2 + (size_t)hV[nt] * len2 * HDIM + (size_t)hdV[nt] * len2 +
               l] = f2bf(acc[mt][nt][r] + bV[nt]);
        }
      }
    }
  }
}

// ---------------------------------------------------------------------------
// Kernel 3: flash attention per (b, h, chunk). 7 waves x 16 query rows.
// 64-key iterations (4 QK tiles/step). Measured-best config (rd11):
// online max (4-shfl cascade) + DEFERRED row-sum (per-lane partial, one
// all-reduce after the loop). Static-max (rd12) measured slower.
// Writes unnormalized O (QPAD x 32, bf16) + per-row (m, l) fp32.
// ---------------------------------------------------------------------------
__global__ __launch_bounds__(448) void attn_kernel(
    const short* __restrict__ Qw, const short* __restrict__ Kw,
    const short* __restrict__ Vw, const int* __restrict__ offs,
    short* __restrict__ Ops, float* __restrict__ Ml, int Bn) {
  int c  = blockIdx.x % NCHUNK;
  int bh = blockIdx.x / NCHUNK;
  int h = bh % NHEAD, b = bh / NHEAD;
  int wave = threadIdx.x >> 6, lane = threadIdx.x & 63;
  int l15 = lane & 15, quad = lane >> 4;

  int off = offs[b], len = offs[b + 1] - off;
  int cl = ((len + NCHUNK * 32 - 1) / (NCHUNK * 32)) * 32;
  int kstart = c * cl;
  int kend   = min(kstart + cl, len);

  const short* Kh = Kw + (size_t)off * DM + (size_t)h * len * HDIM;
  const short* Vh = Vw + (size_t)off * DM + (size_t)h * len * HDIM;

  int row16 = wave * 16 + l15;
  bf16x8 aq = *(const bf16x8*)(
      Qw + (((size_t)b * NHEAD + h) * QPAD + row16) * HDIM + quad * 8);

  f32x4 o[2];
#pragma unroll
  for (int j = 0; j < 2; j++) o[j] = (f32x4){0.f, 0.f, 0.f, 0.f};
  float mrun[4], lrun[4];  // lrun = PER-LANE partial sum (reduced at end)
#pragma unroll
  for (int r = 0; r < 4; r++) { mrun[r] = -1e30f; lrun[r] = 0.f; }

  __shared__ __align__(16) short plds[7][16][72];  // wave-private P transpose

  for (int kb = kstart; kb < kend; kb += 64) {
    bool valid[4];
    bf16x8 bk_[4];
#pragma unroll
    for (int nt = 0; nt < 4; nt++) {
      int key = kb + nt * 16 + l15;
      valid[nt] = key < kend;
      bk_[nt] = valid[nt]
                    ? *(const bf16x8*)(Kh + (size_t)key * HDIM + quad * 8)
                    : bzero8();
    }
    f32x4 zero = {0.f, 0.f, 0.f, 0.f};
    f32x4 s[4];
#pragma unroll
    for (int nt = 0; nt < 4; nt++)
      s[nt] = __builtin_amdgcn_mfma_f32_16x16x32_bf16(aq, bk_[nt], zero, 0, 0, 0);
#pragma unroll
    for (int r = 0; r < 4; r++) {
      float v0 = valid[0] ? s[0][r] : -1e30f;
      float v1 = valid[1] ? s[1][r] : -1e30f;
      float v2 = valid[2] ? s[2][r] : -1e30f;
      float v3 = valid[3] ? s[3][r] : -1e30f;
      float t = fmaxf(fmaxf(v0, v1), fmaxf(v2, v3));
      t = fmaxf(t, __shfl_xor(t, 1, 16));
      t = fmaxf(t, __shfl_xor(t, 2, 16));
      t = fmaxf(t, __shfl_xor(t, 4, 16));
      t = fmaxf(t, __shfl_xor(t, 8, 16));
      float mn = fmaxf(mrun[r], t);
      float al = __expf(mrun[r] - mn);      // row-uniform (mn all-reduced)
      float p0 = valid[0] ? __expf(v0 - mn) : 0.f;
      float p1 = valid[1] ? __expf(v1 - mn) : 0.f;
      float p2 = valid[2] ? __expf(v2 - mn) : 0.f;
      float p3 = valid[3] ? __expf(v3 - mn) : 0.f;
      lrun[r] = al * lrun[r] + ((p0 + p1) + (p2 + p3));  // per-lane partial
      mrun[r] = mn;
      o[0][r] *= al;
      o[1][r] *= al;
      plds[wave][quad * 4 + r][l15]      = f2bf(p0);
      plds[wave][quad * 4 + r][16 + l15] = f2bf(p1);
      plds[wave][quad * 4 + r][32 + l15] = f2bf(p2);
      plds[wave][quad * 4 + r][48 + l15] = f2bf(p3);
    }
    bf16x8 pa0 = *(const bf16x8*)&plds[wave][l15][quad * 8];
    bf16x8 pa1 = *(const bf16x8*)&plds[wave][l15][32 + quad * 8];
    bf16x8 bv_[2][2];
#pragma unroll
    for (int half = 0; half < 2; half++) {
#pragma unroll
      for (int ht = 0; ht < 2; ht++) {
        int hd = ht * 16 + l15;
        int k0 = kb + half * 32 + quad * 8;
        const short* p = Vh + (size_t)hd * len + k0;
        if (k0 + 7 < len) {
          bv_[half][ht] = *(const bf16x8*)p;
        } else {
          bf16x8 v;
#pragma unroll
          for (int j = 0; j < 8; j++) v[j] = (k0 + j < len) ? p[j] : (short)0;
          bv_[half][ht] = v;
        }
      }
    }
#pragma unroll
    for (int ht = 0; ht < 2; ht++) {
      o[ht] = __builtin_amdgcn_mfma_f32_16x16x32_bf16(pa0, bv_[0][ht], o[ht],
                                                      0, 0, 0);
      o[ht] = __builtin_amdgcn_mfma_f32_16x16x32_bf16(pa1, bv_[1][ht], o[ht],
                                                      0, 0, 0);
    }
  }

  // final row-sum all-reduce (hoisted out of the loop), once per block
#pragma unroll
  for (int r = 0; r < 4; r++) {
    lrun[r] += __shfl_xor(lrun[r], 1, 16);
    lrun[r] += __shfl_xor(lrun[r], 2, 16);
    lrun[r] += __shfl_xor(lrun[r], 4, 16);
    lrun[r] += __shfl_xor(lrun[r], 8, 16);
  }

#pragma unroll
  for (int r = 0; r < 4; r++) {
    int row = wave * 16 + quad * 4 + r;
    size_t base = (((size_t)c * Bn + b) * NHEAD + h) * QPAD + row;
#pragma unroll
    for (int ht = 0; ht < 2; ht++)
      Ops[base * HDIM + ht * 16 + l15] = f2bf(o[ht][r]);
    if (l15 == 0) {
      Ml[base * 2]     = mrun[r];
      Ml[base * 2 + 1] = lrun[r];
    }
  }
}

// ---------------------------------------------------------------------------
// Kernel 4: chunk combine + out-projection + residual. CQ=4 queries/block
// (measured best rd7/rd8; CQ=2 regressed ~20 us in rd9).
// LDS-staged vectorized Ops/Ml loads.
// ---------------------------------------------------------------------------
__global__ __launch_bounds__(256) void combine_kernel(
    const short* __restrict__ Ops, const float* __restrict__ Ml,
    const float* __restrict__ query, const float* __restrict__ Wo,
    const float* __restrict__ bo, float* __restrict__ out, int Bn, int NQ) {
  int bpb = (NQ + CQ - 1) / CQ;
  int b  = blockIdx.x / bpb;
  int q0 = (blockIdx.x % bpb) * CQ;
  int tid = threadIdx.x;

  __shared__ __align__(16) short opsl[CQ][NCHUNK][DM];  // 16 KB
  __shared__ float mll[NCHUNK][NHEAD][CQ][2];           // 2 KB
  __shared__ __align__(16) float ctx[CQ * DM];          // 4 KB

  for (int t = tid; t < CQ * NCHUNK * (DM / 8); t += 256) {
    int q   = t / (NCHUNK * 32);
    int rem = t % (NCHUNK * 32);
    int c   = rem / 32;
    int v   = rem % 32;           // 8-elem chunk within 256 = h*32+hd0
    int h   = v >> 2;
    int hd0 = (v & 3) * 8;
    int qq = q0 + q;
    if (qq >= NQ) qq = NQ - 1;
    size_t base = (((size_t)c * Bn + b) * NHEAD + h) * QPAD + qq;
    *(bf16x8*)&opsl[q][c][v * 8] = *(const bf16x8*)&Ops[base * HDIM + hd0];
  }
  for (int t = tid; t < CQ * NCHUNK * NHEAD; t += 256) {
    int q   = t / (NCHUNK * NHEAD);
    int rem = t % (NCHUNK * NHEAD);
    int c   = rem / NHEAD;
    int h   = rem % NHEAD;
    int qq = q0 + q;
    if (qq >= NQ) qq = NQ - 1;
    size_t base = (((size_t)c * Bn + b) * NHEAD + h) * QPAD + qq;
    mll[c][h][q][0] = Ml[base * 2];
    mll[c][h][q][1] = Ml[base * 2 + 1];
  }
  __syncthreads();

  int d = tid, h = d >> 5;
#pragma unroll
  for (int qi = 0; qi < CQ; qi++) {
    float M = -1e30f;
#pragma unroll
    for (int c = 0; c < NCHUNK; c++) M = fmaxf(M, mll[c][h][qi][0]);
    float L = 0.f, acc = 0.f;
#pragma unroll
    for (int c = 0; c < NCHUNK; c++) {
      float w = __expf(mll[c][h][qi][0] - M);
      L += mll[c][h][qi][1] * w;
      acc += w * bf2f(opsl[qi][c][d]);
    }
    ctx[qi * DM + d] = (L > 0.f) ? acc / L : 0.f;
  }
  __syncthreads();

  const float* wrow = Wo + (size_t)d * DM;
  float acc[CQ];
  float bias = bo[d];
#pragma unroll
  for (int qi = 0; qi < CQ; qi++) acc[qi] = bias;
  for (int k = 0; k < DM; k += 4) {
    float4 w = *(const float4*)(wrow + k);
#pragma unroll
    for (int qi = 0; qi < CQ; qi++) {
      float4 x = *(const float4*)&ctx[qi * DM + k];
      acc[qi] += x.x * w.x + x.y * w.y + x.z * w.z + x.w * w.w;
    }
  }
#pragma unroll
  for (int qi = 0; qi < CQ; qi++) {
    int q = q0 + qi;
    if (q < NQ)
      out[((size_t)b * NQ + q) * DM + d] =
          acc[qi] + query[((size_t)b * NQ + q) * DM + d];
  }
}

// ---------------------------------------------------------------------------
extern "C" void kernel_launch(void* const* d_in, const int* in_sizes, int n_in,
                              void* d_out, int out_size, void* d_ws,
                              size_t ws_size, hipStream_t stream) {
  const float* src   = (const float*)d_in[0];
  const float* query = (const float*)d_in[1];
  const int*   offs  = (const int*)d_in[2];
  const float* Wq = (const float*)d_in[3];
  const float* bq = (const float*)d_in[4];
  const float* Wk = (const float*)d_in[5];
  const float* bk = (const float*)d_in[6];
  const float* Wv = (const float*)d_in[7];
  const float* bv = (const float*)d_in[8];
  const float* Wo = (const float*)d_in[9];
  const float* bo = (const float*)d_in[10];
  float* out = (float*)d_out;

  int T  = in_sizes[0] / DM;        // total tokens (65536)
  int Bn = in_sizes[2] - 1;         // batch size (16)
  int NQ = in_sizes[1] / (Bn * DM); // queries per sample (100)

  // Workspace layout (~77 MB):
  char* w = (char*)d_ws;
  size_t qsz = (size_t)Bn * NHEAD * QPAD * HDIM * 2;            // 0.92 MB
  size_t ksz = (size_t)T * DM * 2;                              // 33.5 MB
  size_t osz = (size_t)NCHUNK * Bn * NHEAD * QPAD * HDIM * 2;   // 7.3 MB (bf16)
  size_t msz = (size_t)NCHUNK * Bn * NHEAD * QPAD * 2 * 4;      // 0.92 MB
  short* Qw  = (short*)w;
  short* Kw  = (short*)(w + qsz);
  short* Vw  = (short*)(w + qsz + ksz);
  short* Ops = (short*)(w + qsz + 2 * ksz);
  float* Mlp = (float*)(w + qsz + 2 * ksz + osz);
  short* Wkvq = (short*)(w + qsz + 2 * ksz + osz + msz);        // 0.39 MB

  int Mtiles = (T + BM - 1) / BM;
  int groups = (Mtiles + 7) / 8;
  int kvb = groups * 16;                   // kv blocks (2048)
  int qtiles = (Bn * NQ + BM - 1) / BM;    // q-proj MFMA blocks (25)

  wconv_kernel<<<(3 * DM * DM) / (256 * 8), 256, 0, stream>>>(Wk, Wv, Wq,
                                                              Wkvq);
  kv_gemm_kernel<<<kvb + qtiles, 256, 0, stream>>>(
      src, query, Wkvq, bq, bk, bv, offs, Qw, Kw, Vw, T, Bn, NQ, Mtiles, kvb);
  attn_kernel<<<Bn * NHEAD * NCHUNK, 448, 0, stream>>>(Qw, Kw, Vw, offs, Ops,
                                                       Mlp, Bn);
  combine_kernel<<<Bn * ((NQ + CQ - 1) / CQ), 256, 0, stream>>>(
      Ops, Mlp, query, Wo, bo, out, Bn, NQ);
}

// Round 15
// 228.759 us; speedup vs baseline: 1.0729x; 1.0132x over previous
//
#include <hip/hip_runtime.h>
#include <hip/hip_bf16.h>
#include <math.h>

// Problem constants (fixed by the reference's weight shapes):
#define DM     256   // d_model
#define NHEAD  8
#define HDIM   32
#define QPAD   112   // padded query rows per (b,h): 7 waves x 16 rows
#define NCHUNK 8     // L-chunks per (b,h) for flash parallelism
#define BM     64    // kv_gemm M-tile (tokens)
#define BN     256   // kv_gemm N-tile (output cols): ntile 0 = K, 1 = V
#define BK     32    // kv_gemm K-step
#define ALD    264   // As row stride in shorts (256 + 8 pad)
#define CQ     4     // combine queries per block (CQ=2 measured +20us, rd9)
#define MAXB   64    // max batches cached in LDS for epilogue scans

typedef __attribute__((ext_vector_type(8))) short bf16x8;  // 8 bf16 (4 VGPRs)
typedef __attribute__((ext_vector_type(4))) short bf16x4;  // 8B packed store
typedef __attribute__((ext_vector_type(4))) float f32x4;   // 4 fp32 acc

__device__ __forceinline__ short f2bf(float f) {
  union { float f; unsigned u; } x; x.f = f;
  unsigned u = (x.u + 0x7fffu + ((x.u >> 16) & 1u)) >> 16;
  return (short)u;
}
__device__ __forceinline__ float bf2f(short s) {
  union { unsigned u; float f; } x; x.u = ((unsigned)(unsigned short)s) << 16;
  return x.f;
}
__device__ __forceinline__ bf16x8 bzero8() {
  bf16x8 v;
#pragma unroll
  for (int j = 0; j < 8; j++) v[j] = (short)0;
  return v;
}
__device__ __forceinline__ bf16x8 cvt8(const float* p) {
  float4 x0 = *(const float4*)p, x1 = *(const float4*)(p + 4);
  bf16x8 v;
  v[0] = f2bf(x0.x); v[1] = f2bf(x0.y); v[2] = f2bf(x0.z); v[3] = f2bf(x0.w);
  v[4] = f2bf(x1.x); v[5] = f2bf(x1.y); v[6] = f2bf(x1.z); v[7] = f2bf(x1.w);
  return v;
}
__device__ __forceinline__ bf16x8 cvt8s(const float* p, float s) {
  float4 x0 = *(const float4*)p, x1 = *(const float4*)(p + 4);
  bf16x8 v;
  v[0] = f2bf(x0.x * s); v[1] = f2bf(x0.y * s);
  v[2] = f2bf(x0.z * s); v[3] = f2bf(x0.w * s);
  v[4] = f2bf(x1.x * s); v[5] = f2bf(x1.y * s);
  v[6] = f2bf(x1.z * s); v[7] = f2bf(x1.w * s);
  return v;
}

// ---------------------------------------------------------------------------
// Kernel 0: weight convert.  Wkvq[n][k] bf16 (768 rows):
//   n <  256: Wk row n
//   n < 512 : Wv row n-256
//   n < 768 : Wq row n-512, PRE-SCALED by 1/sqrt(32) (folds the q scale)
// ---------------------------------------------------------------------------
__global__ __launch_bounds__(256) void wconv_kernel(
    const float* __restrict__ Wk, const float* __restrict__ Wv,
    const float* __restrict__ Wq, short* __restrict__ Wkvq) {
  int idx = blockIdx.x * 256 + threadIdx.x;
  int e0 = idx * 8;
  const float* p;
  float s = 1.f;
  if (e0 < DM * DM) {
    p = Wk + e0;
  } else if (e0 < 2 * DM * DM) {
    p = Wv + (e0 - DM * DM);
  } else {
    p = Wq + (e0 - 2 * DM * DM);
    s = 0.17677669529663687f;  // 1/sqrt(32)
  }
  *(bf16x8*)(Wkvq + e0) = cvt8s(p, s);
}

// ---------------------------------------------------------------------------
// Kernel 2: fused projection GEMM, 64x256 tiles, 4 waves (1x4 over N).
//   blocks [0, kvb): KV projection (measured-best config): stage ALL of A
//     (64x256 bf16 = 33.8 KB) into LDS once, barrier-free K-loop, B frags
//     from L2-resident bf16 Wkvq straight into MFMA layout. K/V-paired grid
//     (same XCD, 8 IDs apart -> src L2 hit). K: SWAPPED mfma (C^T); V:
//     normal.
//   blocks [kvb, kvb+25): Q projection as MFMA.
// rd15: offs[] cached in LDS (obuf) — the epilogue's ragged-batch scan was
// a per-lane divergent chain of DEPENDENT global loads on the block
// critical path; LDS reads cut each step ~50-250cy -> ~30cy.
// NOTE (rd13 lesson): keep the Q/KV branch layout — reordering it pushed
// VGPR 120->132 across the 128-VGPR occupancy cliff (+14 us).
// ---------------------------------------------------------------------------
__global__ __launch_bounds__(256) void kv_gemm_kernel(
    const float* __restrict__ src, const float* __restrict__ query,
    const short* __restrict__ Wkvq, const float* __restrict__ bq,
    const float* __restrict__ bk, const float* __restrict__ bv,
    const int* __restrict__ offs, short* __restrict__ Qw,
    short* __restrict__ Kw, short* __restrict__ Vw, int T, int Bn, int NQ,
    int Mtiles, int kvb) {
  int bid = blockIdx.x;
  int tid = threadIdx.x;
  int wave = tid >> 6, lane = tid & 63;
  int l15 = lane & 15, quad = lane >> 4;

  bool isQ = (bid >= kvb);
  const float* Asrc;
  int Arows, t0, n0;
  bool swapped;
  bool isK = false;
  if (isQ) {
    int qt = bid - kvb;
    t0 = qt * BM;
    Asrc = query;
    Arows = Bn * NQ;
    n0 = 2 * DM;       // Wq rows of Wkvq
    swapped = true;    // C^T epilogue
  } else {
    int mtile = (bid >> 4) * 8 + (bid & 7);
    int ntile = (bid >> 3) & 1;
    if (mtile >= Mtiles) return;
    t0 = mtile * BM;
    n0 = ntile * BN;   // 0 => K cols, 256 => V cols
    isK = (ntile == 0);
    swapped = isK;
    Asrc = src;
    Arows = T;
  }

  __shared__ __align__(16) short As[BM * ALD];  // full-K A tile, bf16
  __shared__ int obuf[MAXB + 1];                // offs cache for epilogue

  f32x4 acc[4][4];
#pragma unroll
  for (int i = 0; i < 4; i++)
#pragma unroll
    for (int j = 0; j < 4; j++) acc[i][j] = (f32x4){0.f, 0.f, 0.f, 0.f};

  // ---- prologue: stage all of A (fp32 -> bf16) + offs, one barrier ----
  {
    int arow = tid >> 2, ac4 = tid & 3;
    int atok = t0 + arow;
    if (atok >= Arows) atok = Arows - 1;
    const float* arp = Asrc + (size_t)atok * DM;
#pragma unroll
    for (int r = 0; r < 4; r++) {
      int c0 = r * 64 + ac4 * 16;
      const float* p = arp + c0;
      bf16x8 v0 = cvt8(p);
      bf16x8 v1 = cvt8(p + 8);
      *(bf16x8*)&As[arow * ALD + c0]     = v0;
      *(bf16x8*)&As[arow * ALD + c0 + 8] = v1;
    }
    if (tid <= Bn && tid <= MAXB) obuf[tid] = offs[tid];
  }
  __syncthreads();

  // ---- barrier-free K-loop: B from bf16 Wkvq (L2), A from LDS ----
  const short* bptr = Wkvq + (size_t)(n0 + wave * 64 + l15) * DM + quad * 8;
#pragma unroll
  for (int kk = 0; kk < DM; kk += BK) {
    bf16x8 bf_[4];
#pragma unroll
    for (int nt = 0; nt < 4; nt++)
      bf_[nt] = *(const bf16x8*)(bptr + (size_t)nt * 16 * DM + kk);
    bf16x8 af[4];
#pragma unroll
    for (int mt = 0; mt < 4; mt++)
      af[mt] = *(const bf16x8*)&As[(mt * 16 + l15) * ALD + kk + quad * 8];
    if (swapped) {
#pragma unroll
      for (int mt = 0; mt < 4; mt++)
#pragma unroll
        for (int nt = 0; nt < 4; nt++)
          acc[mt][nt] = __builtin_amdgcn_mfma_f32_16x16x32_bf16(
              bf_[nt], af[mt], acc[mt][nt], 0, 0, 0);  // C^T
    } else {
#pragma unroll
      for (int mt = 0; mt < 4; mt++)
#pragma unroll
        for (int nt = 0; nt < 4; nt++)
          acc[mt][nt] = __builtin_amdgcn_mfma_f32_16x16x32_bf16(
              af[mt], bf_[nt], acc[mt][nt], 0, 0, 0);
    }
  }

  if (isQ) {
    // C^T: lane l15 = query row (within 16), reg r = hd offset quad*4+r.
    const float scale = 0.17677669529663687f;
    float bq4[4][4];
    int hQ[4], hdQ[4];
#pragma unroll
    for (int nt = 0; nt < 4; nt++) {
      int nbq = wave * 64 + nt * 16 + quad * 4;
      float4 b4 = *(const float4*)(bq + nbq);
      bq4[nt][0] = b4.x * scale; bq4[nt][1] = b4.y * scale;
      bq4[nt][2] = b4.z * scale; bq4[nt][3] = b4.w * scale;
      hQ[nt] = nbq >> 5;
      hdQ[nt] = nbq & 31;
    }
#pragma unroll
    for (int mt = 0; mt < 4; mt++) {
      int row = t0 + mt * 16 + l15;
      if (row >= Arows) continue;
      int b = row / NQ;
      int q = row - b * NQ;
#pragma unroll
      for (int nt = 0; nt < 4; nt++) {
        bf16x4 p;
#pragma unroll
        for (int r = 0; r < 4; r++) p[r] = f2bf(acc[mt][nt][r] + bq4[nt][r]);
        *(bf16x4*)&Qw[(((size_t)b * NHEAD + hQ[nt]) * QPAD + q) * HDIM +
                      hdQ[nt]] = p;
      }
    }
  } else if (isK) {
    const float* bias = bk;
    // C^T: lane l15 = token (within 16), reg r = hd offset quad*4+r.
    float bk4[4][4];
    int hK[4], hdK[4];
#pragma unroll
    for (int nt = 0; nt < 4; nt++) {
      int nbq = wave * 64 + nt * 16 + quad * 4;
      float4 b4 = *(const float4*)(bias + nbq);
      bk4[nt][0] = b4.x; bk4[nt][1] = b4.y; bk4[nt][2] = b4.z; bk4[nt][3] = b4.w;
      hK[nt] = nbq >> 5;
      hdK[nt] = nbq & 31;
    }
    int bcur = 0;
#pragma unroll
    for (int mt = 0; mt < 4; mt++) {
      int tok = t0 + mt * 16 + l15;
      if (tok >= T) continue;
      while (bcur + 1 < Bn && obuf[bcur + 1] <= tok) bcur++;
      int off = obuf[bcur], len = obuf[bcur + 1] - off;
      int l = tok - off;
      size_t bb = (size_t)off * DM;
#pragma unroll
      for (int nt = 0; nt < 4; nt++) {
        bf16x4 p;
#pragma unroll
        for (int r = 0; r < 4; r++) p[r] = f2bf(acc[mt][nt][r] + bk4[nt][r]);
        *(bf16x4*)&Kw[bb + (size_t)hK[nt] * len * HDIM + (size_t)l * HDIM +
                      hdK[nt]] = p;
      }
    }
  } else {
    const float* bias = bv;
    // Normal C: lane l15 = hd (within 16), reg r = token offset quad*4+r.
    float bV[4];
    int hV[4], hdV[4];
#pragma unroll
    for (int nt = 0; nt < 4; nt++) {
      int nb = wave * 64 + nt * 16 + l15;
      bV[nt] = bias[nb];
      hV[nt] = nb >> 5;
      hdV[nt] = nb & 31;
    }
    int bcur = 0;
#pragma unroll
    for (int mt = 0; mt < 4; mt++) {
      int tb = t0 + mt * 16 + quad * 4;
      if (tb >= T) continue;
      while (bcur + 1 < Bn && obuf[bcur + 1] <= tb) bcur++;
      int off = obuf[bcur], len = obuf[bcur + 1] - off;
      size_t bb = (size_t)off * DM;
      bool span = (tb + 3 < obuf[bcur + 1]) && (tb + 3 < T);
      if (span) {
        int l = tb - off;
#pragma unroll
        for (int nt = 0; nt < 4; nt++) {
          size_t idx =
              bb + (size_t)hV[nt] * len * HDIM + (size_t)hdV[nt] * len + l;
          bf16x4 p;
#pragma unroll
          for (int r = 0; r < 4; r++) p[r] = f2bf(acc[mt][nt][r] + bV[nt]);
          if ((idx & 3) == 0) {
            *(bf16x4*)&Vw[idx] = p;
          } else {
#pragma unroll
            for (int r = 0; r < 4; r++) Vw[idx + r] = p[r];
          }
        }
      } else {
        int bc2 = bcur;
#pragma unroll
        for (int r = 0; r < 4; r++) {
          int tok = tb + r;
          if (tok >= T) continue;
          while (bc2 + 1 < Bn && obuf[bc2 + 1] <= tok) bc2++;
          int off2 = obuf[bc2], len2 = obuf[bc2 + 1] - off2;
          int l = tok - off2;
          size_t bb2 = (size_t)off2 * DM;
#pragma unroll
          for (int nt = 0; nt < 4; nt++)
            Vw[bb2 + (size_t)hV[nt] * len2 * HDIM + (size_t)hdV[nt] * len2 +
               l] = f2bf(acc[mt][nt][r] + bV[nt]);
        }
      }
    }
  }
}

// ---------------------------------------------------------------------------
// Kernel 3: flash attention per (b, h, chunk). 7 waves x 16 query rows.
// 64-key iterations (4 QK tiles/step). Measured-best config (rd11):
// online max (4-shfl cascade) + DEFERRED row-sum (per-lane partial, one
// all-reduce after the loop). Static-max (rd12) measured slower.
// Writes unnormalized O (QPAD x 32, bf16) + per-row (m, l) fp32.
// ---------------------------------------------------------------------------
__global__ __launch_bounds__(448) void attn_kernel(
    const short* __restrict__ Qw, const short* __restrict__ Kw,
    const short* __restrict__ Vw, const int* __restrict__ offs,
    short* __restrict__ Ops, float* __restrict__ Ml, int Bn) {
  int c  = blockIdx.x % NCHUNK;
  int bh = blockIdx.x / NCHUNK;
  int h = bh % NHEAD, b = bh / NHEAD;
  int wave = threadIdx.x >> 6, lane = threadIdx.x & 63;
  int l15 = lane & 15, quad = lane >> 4;

  int off = offs[b], len = offs[b + 1] - off;
  int cl = ((len + NCHUNK * 32 - 1) / (NCHUNK * 32)) * 32;
  int kstart = c * cl;
  int kend   = min(kstart + cl, len);

  const short* Kh = Kw + (size_t)off * DM + (size_t)h * len * HDIM;
  const short* Vh = Vw + (size_t)off * DM + (size_t)h * len * HDIM;

  int row16 = wave * 16 + l15;
  bf16x8 aq = *(const bf16x8*)(
      Qw + (((size_t)b * NHEAD + h) * QPAD + row16) * HDIM + quad * 8);

  f32x4 o[2];
#pragma unroll
  for (int j = 0; j < 2; j++) o[j] = (f32x4){0.f, 0.f, 0.f, 0.f};
  float mrun[4], lrun[4];  // lrun = PER-LANE partial sum (reduced at end)
#pragma unroll
  for (int r = 0; r < 4; r++) { mrun[r] = -1e30f; lrun[r] = 0.f; }

  __shared__ __align__(16) short plds[7][16][72];  // wave-private P transpose

  for (int kb = kstart; kb < kend; kb += 64) {
    bool valid[4];
    bf16x8 bk_[4];
#pragma unroll
    for (int nt = 0; nt < 4; nt++) {
      int key = kb + nt * 16 + l15;
      valid[nt] = key < kend;
      bk_[nt] = valid[nt]
                    ? *(const bf16x8*)(Kh + (size_t)key * HDIM + quad * 8)
                    : bzero8();
    }
    f32x4 zero = {0.f, 0.f, 0.f, 0.f};
    f32x4 s[4];
#pragma unroll
    for (int nt = 0; nt < 4; nt++)
      s[nt] = __builtin_amdgcn_mfma_f32_16x16x32_bf16(aq, bk_[nt], zero, 0, 0, 0);
#pragma unroll
    for (int r = 0; r < 4; r++) {
      float v0 = valid[0] ? s[0][r] : -1e30f;
      float v1 = valid[1] ? s[1][r] : -1e30f;
      float v2 = valid[2] ? s[2][r] : -1e30f;
      float v3 = valid[3] ? s[3][r] : -1e30f;
      float t = fmaxf(fmaxf(v0, v1), fmaxf(v2, v3));
      t = fmaxf(t, __shfl_xor(t, 1, 16));
      t = fmaxf(t, __shfl_xor(t, 2, 16));
      t = fmaxf(t, __shfl_xor(t, 4, 16));
      t = fmaxf(t, __shfl_xor(t, 8, 16));
      float mn = fmaxf(mrun[r], t);
      float al = __expf(mrun[r] - mn);      // row-uniform (mn all-reduced)
      float p0 = valid[0] ? __expf(v0 - mn) : 0.f;
      float p1 = valid[1] ? __expf(v1 - mn) : 0.f;
      float p2 = valid[2] ? __expf(v2 - mn) : 0.f;
      float p3 = valid[3] ? __expf(v3 - mn) : 0.f;
      lrun[r] = al * lrun[r] + ((p0 + p1) + (p2 + p3));  // per-lane partial
      mrun[r] = mn;
      o[0][r] *= al;
      o[1][r] *= al;
      plds[wave][quad * 4 + r][l15]      = f2bf(p0);
      plds[wave][quad * 4 + r][16 + l15] = f2bf(p1);
      plds[wave][quad * 4 + r][32 + l15] = f2bf(p2);
      plds[wave][quad * 4 + r][48 + l15] = f2bf(p3);
    }
    bf16x8 pa0 = *(const bf16x8*)&plds[wave][l15][quad * 8];
    bf16x8 pa1 = *(const bf16x8*)&plds[wave][l15][32 + quad * 8];
    bf16x8 bv_[2][2];
#pragma unroll
    for (int half = 0; half < 2; half++) {
#pragma unroll
      for (int ht = 0; ht < 2; ht++) {
        int hd = ht * 16 + l15;
        int k0 = kb + half * 32 + quad * 8;
        const short* p = Vh + (size_t)hd * len + k0;
        if (k0 + 7 < len) {
          bv_[half][ht] = *(const bf16x8*)p;
        } else {
          bf16x8 v;
#pragma unroll
          for (int j = 0; j < 8; j++) v[j] = (k0 + j < len) ? p[j] : (short)0;
          bv_[half][ht] = v;
        }
      }
    }
#pragma unroll
    for (int ht = 0; ht < 2; ht++) {
      o[ht] = __builtin_amdgcn_mfma_f32_16x16x32_bf16(pa0, bv_[0][ht], o[ht],
                                                      0, 0, 0);
      o[ht] = __builtin_amdgcn_mfma_f32_16x16x32_bf16(pa1, bv_[1][ht], o[ht],
                                                      0, 0, 0);
    }
  }

  // final row-sum all-reduce (hoisted out of the loop), once per block
#pragma unroll
  for (int r = 0; r < 4; r++) {
    lrun[r] += __shfl_xor(lrun[r], 1, 16);
    lrun[r] += __shfl_xor(lrun[r], 2, 16);
    lrun[r] += __shfl_xor(lrun[r], 4, 16);
    lrun[r] += __shfl_xor(lrun[r], 8, 16);
  }

#pragma unroll
  for (int r = 0; r < 4; r++) {
    int row = wave * 16 + quad * 4 + r;
    size_t base = (((size_t)c * Bn + b) * NHEAD + h) * QPAD + row;
#pragma unroll
    for (int ht = 0; ht < 2; ht++)
      Ops[base * HDIM + ht * 16 + l15] = f2bf(o[ht][r]);
    if (l15 == 0) {
      Ml[base * 2]     = mrun[r];
      Ml[base * 2 + 1] = lrun[r];
    }
  }
}

// ---------------------------------------------------------------------------
// Kernel 4: chunk combine + out-projection + residual. CQ=4 queries/block
// (measured best rd7/rd8; CQ=2 regressed ~20 us in rd9).
// LDS-staged vectorized Ops/Ml loads.
// ---------------------------------------------------------------------------
__global__ __launch_bounds__(256) void combine_kernel(
    const short* __restrict__ Ops, const float* __restrict__ Ml,
    const float* __restrict__ query, const float* __restrict__ Wo,
    const float* __restrict__ bo, float* __restrict__ out, int Bn, int NQ) {
  int bpb = (NQ + CQ - 1) / CQ;
  int b  = blockIdx.x / bpb;
  int q0 = (blockIdx.x % bpb) * CQ;
  int tid = threadIdx.x;

  __shared__ __align__(16) short opsl[CQ][NCHUNK][DM];  // 16 KB
  __shared__ float mll[NCHUNK][NHEAD][CQ][2];           // 2 KB
  __shared__ __align__(16) float ctx[CQ * DM];          // 4 KB

  for (int t = tid; t < CQ * NCHUNK * (DM / 8); t += 256) {
    int q   = t / (NCHUNK * 32);
    int rem = t % (NCHUNK * 32);
    int c   = rem / 32;
    int v   = rem % 32;           // 8-elem chunk within 256 = h*32+hd0
    int h   = v >> 2;
    int hd0 = (v & 3) * 8;
    int qq = q0 + q;
    if (qq >= NQ) qq = NQ - 1;
    size_t base = (((size_t)c * Bn + b) * NHEAD + h) * QPAD + qq;
    *(bf16x8*)&opsl[q][c][v * 8] = *(const bf16x8*)&Ops[base * HDIM + hd0];
  }
  for (int t = tid; t < CQ * NCHUNK * NHEAD; t += 256) {
    int q   = t / (NCHUNK * NHEAD);
    int rem = t % (NCHUNK * NHEAD);
    int c   = rem / NHEAD;
    int h   = rem % NHEAD;
    int qq = q0 + q;
    if (qq >= NQ) qq = NQ - 1;
    size_t base = (((size_t)c * Bn + b) * NHEAD + h) * QPAD + qq;
    mll[c][h][q][0] = Ml[base * 2];
    mll[c][h][q][1] = Ml[base * 2 + 1];
  }
  __syncthreads();

  int d = tid, h = d >> 5;
#pragma unroll
  for (int qi = 0; qi < CQ; qi++) {
    float M = -1e30f;
#pragma unroll
    for (int c = 0; c < NCHUNK; c++) M = fmaxf(M, mll[c][h][qi][0]);
    float L = 0.f, acc = 0.f;
#pragma unroll
    for (int c = 0; c < NCHUNK; c++) {
      float w = __expf(mll[c][h][qi][0] - M);
      L += mll[c][h][qi][1] * w;
      acc += w * bf2f(opsl[qi][c][d]);
    }
    ctx[qi * DM + d] = (L > 0.f) ? acc / L : 0.f;
  }
  __syncthreads();

  const float* wrow = Wo + (size_t)d * DM;
  float acc[CQ];
  float bias = bo[d];
#pragma unroll
  for (int qi = 0; qi < CQ; qi++) acc[qi] = bias;
  for (int k = 0; k < DM; k += 4) {
    float4 w = *(const float4*)(wrow + k);
#pragma unroll
    for (int qi = 0; qi < CQ; qi++) {
      float4 x = *(const float4*)&ctx[qi * DM + k];
      acc[qi] += x.x * w.x + x.y * w.y + x.z * w.z + x.w * w.w;
    }
  }
#pragma unroll
  for (int qi = 0; qi < CQ; qi++) {
    int q = q0 + qi;
    if (q < NQ)
      out[((size_t)b * NQ + q) * DM + d] =
          acc[qi] + query[((size_t)b * NQ + q) * DM + d];
  }
}

// ---------------------------------------------------------------------------
extern "C" void kernel_launch(void* const* d_in, const int* in_sizes, int n_in,
                              void* d_out, int out_size, void* d_ws,
                              size_t ws_size, hipStream_t stream) {
  const float* src   = (const float*)d_in[0];
  const float* query = (const float*)d_in[1];
  const int*   offs  = (const int*)d_in[2];
  const float* Wq = (const float*)d_in[3];
  const float* bq = (const float*)d_in[4];
  const float* Wk = (const float*)d_in[5];
  const float* bk = (const float*)d_in[6];
  const float* Wv = (const float*)d_in[7];
  const float* bv = (const float*)d_in[8];
  const float* Wo = (const float*)d_in[9];
  const float* bo = (const float*)d_in[10];
  float* out = (float*)d_out;

  int T  = in_sizes[0] / DM;        // total tokens (65536)
  int Bn = in_sizes[2] - 1;         // batch size (16)
  int NQ = in_sizes[1] / (Bn * DM); // queries per sample (100)

  // Workspace layout (~77 MB):
  char* w = (char*)d_ws;
  size_t qsz = (size_t)Bn * NHEAD * QPAD * HDIM * 2;            // 0.92 MB
  size_t ksz = (size_t)T * DM * 2;                              // 33.5 MB
  size_t osz = (size_t)NCHUNK * Bn * NHEAD * QPAD * HDIM * 2;   // 7.3 MB (bf16)
  size_t msz = (size_t)NCHUNK * Bn * NHEAD * QPAD * 2 * 4;      // 0.92 MB
  short* Qw  = (short*)w;
  short* Kw  = (short*)(w + qsz);
  short* Vw  = (short*)(w + qsz + ksz);
  short* Ops = (short*)(w + qsz + 2 * ksz);
  float* Mlp = (float*)(w + qsz + 2 * ksz + osz);
  short* Wkvq = (short*)(w + qsz + 2 * ksz + osz + msz);        // 0.39 MB

  int Mtiles = (T + BM - 1) / BM;
  int groups = (Mtiles + 7) / 8;
  int kvb = groups * 16;                   // kv blocks (2048)
  int qtiles = (Bn * NQ + BM - 1) / BM;    // q-proj MFMA blocks (25)

  wconv_kernel<<<(3 * DM * DM) / (256 * 8), 256, 0, stream>>>(Wk, Wv, Wq,
                                                              Wkvq);
  kv_gemm_kernel<<<kvb + qtiles, 256, 0, stream>>>(
      src, query, Wkvq, bq, bk, bv, offs, Qw, Kw, Vw, T, Bn, NQ, Mtiles, kvb);
  attn_kernel<<<Bn * NHEAD * NCHUNK, 448, 0, stream>>>(Qw, Kw, Vw, offs, Ops,
                                                       Mlp, Bn);
  combine_kernel<<<Bn * ((NQ + CQ - 1) / CQ), 256, 0, stream>>>(
      Ops, Mlp, query, Wo, bo, out, Bn, NQ);
}

// Round 16
// 220.173 us; speedup vs baseline: 1.1148x; 1.0390x over previous
//
#include <hip/hip_runtime.h>
#include <hip/hip_bf16.h>
#include <math.h>

// Problem constants (fixed by the reference's weight shapes):
#define DM     256   // d_model
#define NHEAD  8
#define HDIM   32
#define QPAD   112   // padded query rows per (b,h): 7 waves x 16 rows
#define NCHUNK 8     // L-chunks per (b,h) for flash parallelism
#define BM     64    // kv_gemm M-tile (tokens)
#define BN     256   // kv_gemm N-tile (output cols per pass)
#define BK     32    // kv_gemm K-step
#define ALD    264   // As row stride in shorts (256 + 8 pad)
#define CQ     4     // combine queries per block (CQ=2 measured +20us, rd9)
#define MAXB   64    // max batches cached in LDS for epilogue scans

typedef __attribute__((ext_vector_type(8))) short bf16x8;  // 8 bf16 (4 VGPRs)
typedef __attribute__((ext_vector_type(4))) short bf16x4;  // 8B packed store
typedef __attribute__((ext_vector_type(4))) float f32x4;   // 4 fp32 acc

__device__ __forceinline__ short f2bf(float f) {
  union { float f; unsigned u; } x; x.f = f;
  unsigned u = (x.u + 0x7fffu + ((x.u >> 16) & 1u)) >> 16;
  return (short)u;
}
__device__ __forceinline__ float bf2f(short s) {
  union { unsigned u; float f; } x; x.u = ((unsigned)(unsigned short)s) << 16;
  return x.f;
}
__device__ __forceinline__ bf16x8 bzero8() {
  bf16x8 v;
#pragma unroll
  for (int j = 0; j < 8; j++) v[j] = (short)0;
  return v;
}
__device__ __forceinline__ bf16x8 cvt8(const float* p) {
  float4 x0 = *(const float4*)p, x1 = *(const float4*)(p + 4);
  bf16x8 v;
  v[0] = f2bf(x0.x); v[1] = f2bf(x0.y); v[2] = f2bf(x0.z); v[3] = f2bf(x0.w);
  v[4] = f2bf(x1.x); v[5] = f2bf(x1.y); v[6] = f2bf(x1.z); v[7] = f2bf(x1.w);
  return v;
}
__device__ __forceinline__ bf16x8 cvt8s(const float* p, float s) {
  float4 x0 = *(const float4*)p, x1 = *(const float4*)(p + 4);
  bf16x8 v;
  v[0] = f2bf(x0.x * s); v[1] = f2bf(x0.y * s);
  v[2] = f2bf(x0.z * s); v[3] = f2bf(x0.w * s);
  v[4] = f2bf(x1.x * s); v[5] = f2bf(x1.y * s);
  v[6] = f2bf(x1.z * s); v[7] = f2bf(x1.w * s);
  return v;
}

// ---------------------------------------------------------------------------
// Kernel 0: weight convert.  Wkvq[n][k] bf16 (768 rows):
//   n <  256: Wk row n
//   n < 512 : Wv row n-256
//   n < 768 : Wq row n-512, PRE-SCALED by 1/sqrt(32) (folds the q scale)
// ---------------------------------------------------------------------------
__global__ __launch_bounds__(256) void wconv_kernel(
    const float* __restrict__ Wk, const float* __restrict__ Wv,
    const float* __restrict__ Wq, short* __restrict__ Wkvq) {
  int idx = blockIdx.x * 256 + threadIdx.x;
  int e0 = idx * 8;
  const float* p;
  float s = 1.f;
  if (e0 < DM * DM) {
    p = Wk + e0;
  } else if (e0 < 2 * DM * DM) {
    p = Wv + (e0 - DM * DM);
  } else {
    p = Wq + (e0 - 2 * DM * DM);
    s = 0.17677669529663687f;  // 1/sqrt(32)
  }
  *(bf16x8*)(Wkvq + e0) = cvt8s(p, s);
}

// ---------------------------------------------------------------------------
// Kernel 2: fused projection GEMM, 64x256 tiles, 4 waves (1x4 over N).
// rd16: K and V MERGED into one block per mtile — stage A once, then two
// sequential accumulate->epilogue passes (pass 0: K cols, swapped C^T;
// pass 1: V cols, normal), reusing the same acc registers. Halves the
// prologue count (A-stage latency chain) and the grid (2048+25 -> 1024+25),
// dropping block-round count ~2.7 -> ~1.4 on 3-blocks/CU residency.
// Pairing swizzle removed (reuse is now intra-block).
//   blocks [0, kvb=Mtiles): merged KV tile.
//   blocks [kvb, kvb+25): Q projection as MFMA (pass over Wq rows 512-767).
// rd15: offs[] cached in LDS (obuf) for the divergent epilogue scans.
// NOTE (rd13 lesson): VGPR must stay <=128 (occupancy cliff). KLOOP/SWAP is
// compile-time so no runtime flag perturbs regalloc.
// ---------------------------------------------------------------------------
#define ZERO_ACC()                                          \
  _Pragma("unroll")                                         \
  for (int zi = 0; zi < 4; zi++)                            \
    _Pragma("unroll")                                       \
    for (int zj = 0; zj < 4; zj++)                          \
      acc[zi][zj] = (f32x4){0.f, 0.f, 0.f, 0.f};

#define KLOOP(N0, SWAP)                                                      \
  {                                                                          \
    const short* bptr =                                                      \
        Wkvq + (size_t)((N0) + wave * 64 + l15) * DM + quad * 8;             \
    _Pragma("unroll")                                                        \
    for (int kk = 0; kk < DM; kk += BK) {                                    \
      bf16x8 bf_[4];                                                         \
      _Pragma("unroll")                                                      \
      for (int nt = 0; nt < 4; nt++)                                         \
        bf_[nt] = *(const bf16x8*)(bptr + (size_t)nt * 16 * DM + kk);        \
      bf16x8 af[4];                                                          \
      _Pragma("unroll")                                                      \
      for (int mt = 0; mt < 4; mt++)                                         \
        af[mt] = *(const bf16x8*)&As[(mt * 16 + l15) * ALD + kk + quad * 8]; \
      if (SWAP) {                                                            \
        _Pragma("unroll")                                                    \
        for (int mt = 0; mt < 4; mt++)                                       \
          _Pragma("unroll")                                                  \
          for (int nt = 0; nt < 4; nt++)                                     \
            acc[mt][nt] = __builtin_amdgcn_mfma_f32_16x16x32_bf16(           \
                bf_[nt], af[mt], acc[mt][nt], 0, 0, 0);                      \
      } else {                                                               \
        _Pragma("unroll")                                                    \
        for (int mt = 0; mt < 4; mt++)                                       \
          _Pragma("unroll")                                                  \
          for (int nt = 0; nt < 4; nt++)                                     \
            acc[mt][nt] = __builtin_amdgcn_mfma_f32_16x16x32_bf16(           \
                af[mt], bf_[nt], acc[mt][nt], 0, 0, 0);                      \
      }                                                                      \
    }                                                                        \
  }

__global__ __launch_bounds__(256) void kv_gemm_kernel(
    const float* __restrict__ src, const float* __restrict__ query,
    const short* __restrict__ Wkvq, const float* __restrict__ bq,
    const float* __restrict__ bk, const float* __restrict__ bv,
    const int* __restrict__ offs, short* __restrict__ Qw,
    short* __restrict__ Kw, short* __restrict__ Vw, int T, int Bn, int NQ,
    int Mtiles, int kvb) {
  int bid = blockIdx.x;
  int tid = threadIdx.x;
  int wave = tid >> 6, lane = tid & 63;
  int l15 = lane & 15, quad = lane >> 4;

  bool isQ = (bid >= kvb);
  const float* Asrc;
  int Arows, t0;
  if (isQ) {
    t0 = (bid - kvb) * BM;
    Asrc = query;
    Arows = Bn * NQ;
  } else {
    t0 = bid * BM;
    Asrc = src;
    Arows = T;
  }

  __shared__ __align__(16) short As[BM * ALD];  // full-K A tile, bf16
  __shared__ int obuf[MAXB + 1];                // offs cache for epilogue

  f32x4 acc[4][4];

  // ---- prologue: stage all of A (fp32 -> bf16) + offs, one barrier ----
  {
    int arow = tid >> 2, ac4 = tid & 3;
    int atok = t0 + arow;
    if (atok >= Arows) atok = Arows - 1;
    const float* arp = Asrc + (size_t)atok * DM;
#pragma unroll
    for (int r = 0; r < 4; r++) {
      int c0 = r * 64 + ac4 * 16;
      const float* p = arp + c0;
      bf16x8 v0 = cvt8(p);
      bf16x8 v1 = cvt8(p + 8);
      *(bf16x8*)&As[arow * ALD + c0]     = v0;
      *(bf16x8*)&As[arow * ALD + c0 + 8] = v1;
    }
    if (tid <= Bn && tid <= MAXB) obuf[tid] = offs[tid];
  }
  __syncthreads();

  if (isQ) {
    // ---- Q pass: Wq rows 512-767, swapped C^T epilogue ----
    ZERO_ACC();
    KLOOP(2 * DM, 1);
    const float scale = 0.17677669529663687f;
    float bq4[4][4];
    int hQ[4], hdQ[4];
#pragma unroll
    for (int nt = 0; nt < 4; nt++) {
      int nbq = wave * 64 + nt * 16 + quad * 4;
      float4 b4 = *(const float4*)(bq + nbq);
      bq4[nt][0] = b4.x * scale; bq4[nt][1] = b4.y * scale;
      bq4[nt][2] = b4.z * scale; bq4[nt][3] = b4.w * scale;
      hQ[nt] = nbq >> 5;
      hdQ[nt] = nbq & 31;
    }
#pragma unroll
    for (int mt = 0; mt < 4; mt++) {
      int row = t0 + mt * 16 + l15;
      if (row >= Arows) continue;
      int b = row / NQ;
      int q = row - b * NQ;
#pragma unroll
      for (int nt = 0; nt < 4; nt++) {
        bf16x4 p;
#pragma unroll
        for (int r = 0; r < 4; r++) p[r] = f2bf(acc[mt][nt][r] + bq4[nt][r]);
        *(bf16x4*)&Qw[(((size_t)b * NHEAD + hQ[nt]) * QPAD + q) * HDIM +
                      hdQ[nt]] = p;
      }
    }
    return;
  }

  // ---- K pass: Wk rows 0-255, swapped C^T epilogue ----
  ZERO_ACC();
  KLOOP(0, 1);
  {
    const float* bias = bk;
    float bk4[4][4];
    int hK[4], hdK[4];
#pragma unroll
    for (int nt = 0; nt < 4; nt++) {
      int nbq = wave * 64 + nt * 16 + quad * 4;
      float4 b4 = *(const float4*)(bias + nbq);
      bk4[nt][0] = b4.x; bk4[nt][1] = b4.y; bk4[nt][2] = b4.z; bk4[nt][3] = b4.w;
      hK[nt] = nbq >> 5;
      hdK[nt] = nbq & 31;
    }
    int bcur = 0;
#pragma unroll
    for (int mt = 0; mt < 4; mt++) {
      int tok = t0 + mt * 16 + l15;
      if (tok >= T) continue;
      while (bcur + 1 < Bn && obuf[bcur + 1] <= tok) bcur++;
      int off = obuf[bcur], len = obuf[bcur + 1] - off;
      int l = tok - off;
      size_t bb = (size_t)off * DM;
#pragma unroll
      for (int nt = 0; nt < 4; nt++) {
        bf16x4 p;
#pragma unroll
        for (int r = 0; r < 4; r++) p[r] = f2bf(acc[mt][nt][r] + bk4[nt][r]);
        *(bf16x4*)&Kw[bb + (size_t)hK[nt] * len * HDIM + (size_t)l * HDIM +
                      hdK[nt]] = p;
      }
    }
  }

  // ---- V pass: Wv rows 256-511, normal epilogue ----
  ZERO_ACC();
  KLOOP(DM, 0);
  {
    const float* bias = bv;
    float bV[4];
    int hV[4], hdV[4];
#pragma unroll
    for (int nt = 0; nt < 4; nt++) {
      int nb = wave * 64 + nt * 16 + l15;
      bV[nt] = bias[nb];
      hV[nt] = nb >> 5;
      hdV[nt] = nb & 31;
    }
    int bcur = 0;
#pragma unroll
    for (int mt = 0; mt < 4; mt++) {
      int tb = t0 + mt * 16 + quad * 4;
      if (tb >= T) continue;
      while (bcur + 1 < Bn && obuf[bcur + 1] <= tb) bcur++;
      int off = obuf[bcur], len = obuf[bcur + 1] - off;
      size_t bb = (size_t)off * DM;
      bool span = (tb + 3 < obuf[bcur + 1]) && (tb + 3 < T);
      if (span) {
        int l = tb - off;
#pragma unroll
        for (int nt = 0; nt < 4; nt++) {
          size_t idx =
              bb + (size_t)hV[nt] * len * HDIM + (size_t)hdV[nt] * len + l;
          bf16x4 p;
#pragma unroll
          for (int r = 0; r < 4; r++) p[r] = f2bf(acc[mt][nt][r] + bV[nt]);
          if ((idx & 3) == 0) {
            *(bf16x4*)&Vw[idx] = p;
          } else {
#pragma unroll
            for (int r = 0; r < 4; r++) Vw[idx + r] = p[r];
          }
        }
      } else {
        int bc2 = bcur;
#pragma unroll
        for (int r = 0; r < 4; r++) {
          int tok = tb + r;
          if (tok >= T) continue;
          while (bc2 + 1 < Bn && obuf[bc2 + 1] <= tok) bc2++;
          int off2 = obuf[bc2], len2 = obuf[bc2 + 1] - off2;
          int l = tok - off2;
          size_t bb2 = (size_t)off2 * DM;
#pragma unroll
          for (int nt = 0; nt < 4; nt++)
            Vw[bb2 + (size_t)hV[nt] * len2 * HDIM + (size_t)hdV[nt] * len2 +
               l] = f2bf(acc[mt][nt][r] + bV[nt]);
        }
      }
    }
  }
}

// ---------------------------------------------------------------------------
// Kernel 3: flash attention per (b, h, chunk). 7 waves x 16 query rows.
// 64-key iterations (4 QK tiles/step). Measured-best config (rd11):
// online max (4-shfl cascade) + DEFERRED row-sum (per-lane partial, one
// all-reduce after the loop). Static-max (rd12) measured slower.
// Writes unnormalized O (QPAD x 32, bf16) + per-row (m, l) fp32.
// ---------------------------------------------------------------------------
__global__ __launch_bounds__(448) void attn_kernel(
    const short* __restrict__ Qw, const short* __restrict__ Kw,
    const short* __restrict__ Vw, const int* __restrict__ offs,
    short* __restrict__ Ops, float* __restrict__ Ml, int Bn) {
  int c  = blockIdx.x % NCHUNK;
  int bh = blockIdx.x / NCHUNK;
  int h = bh % NHEAD, b = bh / NHEAD;
  int wave = threadIdx.x >> 6, lane = threadIdx.x & 63;
  int l15 = lane & 15, quad = lane >> 4;

  int off = offs[b], len = offs[b + 1] - off;
  int cl = ((len + NCHUNK * 32 - 1) / (NCHUNK * 32)) * 32;
  int kstart = c * cl;
  int kend   = min(kstart + cl, len);

  const short* Kh = Kw + (size_t)off * DM + (size_t)h * len * HDIM;
  const short* Vh = Vw + (size_t)off * DM + (size_t)h * len * HDIM;

  int row16 = wave * 16 + l15;
  bf16x8 aq = *(const bf16x8*)(
      Qw + (((size_t)b * NHEAD + h) * QPAD + row16) * HDIM + quad * 8);

  f32x4 o[2];
#pragma unroll
  for (int j = 0; j < 2; j++) o[j] = (f32x4){0.f, 0.f, 0.f, 0.f};
  float mrun[4], lrun[4];  // lrun = PER-LANE partial sum (reduced at end)
#pragma unroll
  for (int r = 0; r < 4; r++) { mrun[r] = -1e30f; lrun[r] = 0.f; }

  __shared__ __align__(16) short plds[7][16][72];  // wave-private P transpose

  for (int kb = kstart; kb < kend; kb += 64) {
    bool valid[4];
    bf16x8 bk_[4];
#pragma unroll
    for (int nt = 0; nt < 4; nt++) {
      int key = kb + nt * 16 + l15;
      valid[nt] = key < kend;
      bk_[nt] = valid[nt]
                    ? *(const bf16x8*)(Kh + (size_t)key * HDIM + quad * 8)
                    : bzero8();
    }
    f32x4 zero = {0.f, 0.f, 0.f, 0.f};
    f32x4 s[4];
#pragma unroll
    for (int nt = 0; nt < 4; nt++)
      s[nt] = __builtin_amdgcn_mfma_f32_16x16x32_bf16(aq, bk_[nt], zero, 0, 0, 0);
#pragma unroll
    for (int r = 0; r < 4; r++) {
      float v0 = valid[0] ? s[0][r] : -1e30f;
      float v1 = valid[1] ? s[1][r] : -1e30f;
      float v2 = valid[2] ? s[2][r] : -1e30f;
      float v3 = valid[3] ? s[3][r] : -1e30f;
      float t = fmaxf(fmaxf(v0, v1), fmaxf(v2, v3));
      t = fmaxf(t, __shfl_xor(t, 1, 16));
      t = fmaxf(t, __shfl_xor(t, 2, 16));
      t = fmaxf(t, __shfl_xor(t, 4, 16));
      t = fmaxf(t, __shfl_xor(t, 8, 16));
      float mn = fmaxf(mrun[r], t);
      float al = __expf(mrun[r] - mn);      // row-uniform (mn all-reduced)
      float p0 = valid[0] ? __expf(v0 - mn) : 0.f;
      float p1 = valid[1] ? __expf(v1 - mn) : 0.f;
      float p2 = valid[2] ? __expf(v2 - mn) : 0.f;
      float p3 = valid[3] ? __expf(v3 - mn) : 0.f;
      lrun[r] = al * lrun[r] + ((p0 + p1) + (p2 + p3));  // per-lane partial
      mrun[r] = mn;
      o[0][r] *= al;
      o[1][r] *= al;
      plds[wave][quad * 4 + r][l15]      = f2bf(p0);
      plds[wave][quad * 4 + r][16 + l15] = f2bf(p1);
      plds[wave][quad * 4 + r][32 + l15] = f2bf(p2);
      plds[wave][quad * 4 + r][48 + l15] = f2bf(p3);
    }
    bf16x8 pa0 = *(const bf16x8*)&plds[wave][l15][quad * 8];
    bf16x8 pa1 = *(const bf16x8*)&plds[wave][l15][32 + quad * 8];
    bf16x8 bv_[2][2];
#pragma unroll
    for (int half = 0; half < 2; half++) {
#pragma unroll
      for (int ht = 0; ht < 2; ht++) {
        int hd = ht * 16 + l15;
        int k0 = kb + half * 32 + quad * 8;
        const short* p = Vh + (size_t)hd * len + k0;
        if (k0 + 7 < len) {
          bv_[half][ht] = *(const bf16x8*)p;
        } else {
          bf16x8 v;
#pragma unroll
          for (int j = 0; j < 8; j++) v[j] = (k0 + j < len) ? p[j] : (short)0;
          bv_[half][ht] = v;
        }
      }
    }
#pragma unroll
    for (int ht = 0; ht < 2; ht++) {
      o[ht] = __builtin_amdgcn_mfma_f32_16x16x32_bf16(pa0, bv_[0][ht], o[ht],
                                                      0, 0, 0);
      o[ht] = __builtin_amdgcn_mfma_f32_16x16x32_bf16(pa1, bv_[1][ht], o[ht],
                                                      0, 0, 0);
    }
  }

  // final row-sum all-reduce (hoisted out of the loop), once per block
#pragma unroll
  for (int r = 0; r < 4; r++) {
    lrun[r] += __shfl_xor(lrun[r], 1, 16);
    lrun[r] += __shfl_xor(lrun[r], 2, 16);
    lrun[r] += __shfl_xor(lrun[r], 4, 16);
    lrun[r] += __shfl_xor(lrun[r], 8, 16);
  }

#pragma unroll
  for (int r = 0; r < 4; r++) {
    int row = wave * 16 + quad * 4 + r;
    size_t base = (((size_t)c * Bn + b) * NHEAD + h) * QPAD + row;
#pragma unroll
    for (int ht = 0; ht < 2; ht++)
      Ops[base * HDIM + ht * 16 + l15] = f2bf(o[ht][r]);
    if (l15 == 0) {
      Ml[base * 2]     = mrun[r];
      Ml[base * 2 + 1] = lrun[r];
    }
  }
}

// ---------------------------------------------------------------------------
// Kernel 4: chunk combine + out-projection + residual. CQ=4 queries/block
// (measured best rd7/rd8; CQ=2 regressed ~20 us in rd9).
// LDS-staged vectorized Ops/Ml loads.
// ---------------------------------------------------------------------------
__global__ __launch_bounds__(256) void combine_kernel(
    const short* __restrict__ Ops, const float* __restrict__ Ml,
    const float* __restrict__ query, const float* __restrict__ Wo,
    const float* __restrict__ bo, float* __restrict__ out, int Bn, int NQ) {
  int bpb = (NQ + CQ - 1) / CQ;
  int b  = blockIdx.x / bpb;
  int q0 = (blockIdx.x % bpb) * CQ;
  int tid = threadIdx.x;

  __shared__ __align__(16) short opsl[CQ][NCHUNK][DM];  // 16 KB
  __shared__ float mll[NCHUNK][NHEAD][CQ][2];           // 2 KB
  __shared__ __align__(16) float ctx[CQ * DM];          // 4 KB

  for (int t = tid; t < CQ * NCHUNK * (DM / 8); t += 256) {
    int q   = t / (NCHUNK * 32);
    int rem = t % (NCHUNK * 32);
    int c   = rem / 32;
    int v   = rem % 32;           // 8-elem chunk within 256 = h*32+hd0
    int h   = v >> 2;
    int hd0 = (v & 3) * 8;
    int qq = q0 + q;
    if (qq >= NQ) qq = NQ - 1;
    size_t base = (((size_t)c * Bn + b) * NHEAD + h) * QPAD + qq;
    *(bf16x8*)&opsl[q][c][v * 8] = *(const bf16x8*)&Ops[base * HDIM + hd0];
  }
  for (int t = tid; t < CQ * NCHUNK * NHEAD; t += 256) {
    int q   = t / (NCHUNK * NHEAD);
    int rem = t % (NCHUNK * NHEAD);
    int c   = rem / NHEAD;
    int h   = rem % NHEAD;
    int qq = q0 + q;
    if (qq >= NQ) qq = NQ - 1;
    size_t base = (((size_t)c * Bn + b) * NHEAD + h) * QPAD + qq;
    mll[c][h][q][0] = Ml[base * 2];
    mll[c][h][q][1] = Ml[base * 2 + 1];
  }
  __syncthreads();

  int d = tid, h = d >> 5;
#pragma unroll
  for (int qi = 0; qi < CQ; qi++) {
    float M = -1e30f;
#pragma unroll
    for (int c = 0; c < NCHUNK; c++) M = fmaxf(M, mll[c][h][qi][0]);
    float L = 0.f, acc = 0.f;
#pragma unroll
    for (int c = 0; c < NCHUNK; c++) {
      float w = __expf(mll[c][h][qi][0] - M);
      L += mll[c][h][qi][1] * w;
      acc += w * bf2f(opsl[qi][c][d]);
    }
    ctx[qi * DM + d] = (L > 0.f) ? acc / L : 0.f;
  }
  __syncthreads();

  const float* wrow = Wo + (size_t)d * DM;
  float acc[CQ];
  float bias = bo[d];
#pragma unroll
  for (int qi = 0; qi < CQ; qi++) acc[qi] = bias;
  for (int k = 0; k < DM; k += 4) {
    float4 w = *(const float4*)(wrow + k);
#pragma unroll
    for (int qi = 0; qi < CQ; qi++) {
      float4 x = *(const float4*)&ctx[qi * DM + k];
      acc[qi] += x.x * w.x + x.y * w.y + x.z * w.z + x.w * w.w;
    }
  }
#pragma unroll
  for (int qi = 0; qi < CQ; qi++) {
    int q = q0 + qi;
    if (q < NQ)
      out[((size_t)b * NQ + q) * DM + d] =
          acc[qi] + query[((size_t)b * NQ + q) * DM + d];
  }
}

// ---------------------------------------------------------------------------
extern "C" void kernel_launch(void* const* d_in, const int* in_sizes, int n_in,
                              void* d_out, int out_size, void* d_ws,
                              size_t ws_size, hipStream_t stream) {
  const float* src   = (const float*)d_in[0];
  const float* query = (const float*)d_in[1];
  const int*   offs  = (const int*)d_in[2];
  const float* Wq = (const float*)d_in[3];
  const float* bq = (const float*)d_in[4];
  const float* Wk = (const float*)d_in[5];
  const float* bk = (const float*)d_in[6];
  const float* Wv = (const float*)d_in[7];
  const float* bv = (const float*)d_in[8];
  const float* Wo = (const float*)d_in[9];
  const float* bo = (const float*)d_in[10];
  float* out = (float*)d_out;

  int T  = in_sizes[0] / DM;        // total tokens (65536)
  int Bn = in_sizes[2] - 1;         // batch size (16)
  int NQ = in_sizes[1] / (Bn * DM); // queries per sample (100)

  // Workspace layout (~77 MB):
  char* w = (char*)d_ws;
  size_t qsz = (size_t)Bn * NHEAD * QPAD * HDIM * 2;            // 0.92 MB
  size_t ksz = (size_t)T * DM * 2;                              // 33.5 MB
  size_t osz = (size_t)NCHUNK * Bn * NHEAD * QPAD * HDIM * 2;   // 7.3 MB (bf16)
  size_t msz = (size_t)NCHUNK * Bn * NHEAD * QPAD * 2 * 4;      // 0.92 MB
  short* Qw  = (short*)w;
  short* Kw  = (short*)(w + qsz);
  short* Vw  = (short*)(w + qsz + ksz);
  short* Ops = (short*)(w + qsz + 2 * ksz);
  float* Mlp = (float*)(w + qsz + 2 * ksz + osz);
  short* Wkvq = (short*)(w + qsz + 2 * ksz + osz + msz);        // 0.39 MB

  int Mtiles = (T + BM - 1) / BM;
  int qtiles = (Bn * NQ + BM - 1) / BM;    // q-proj MFMA blocks (25)

  wconv_kernel<<<(3 * DM * DM) / (256 * 8), 256, 0, stream>>>(Wk, Wv, Wq,
                                                              Wkvq);
  kv_gemm_kernel<<<Mtiles + qtiles, 256, 0, stream>>>(
      src, query, Wkvq, bq, bk, bv, offs, Qw, Kw, Vw, T, Bn, NQ, Mtiles,
      Mtiles);
  attn_kernel<<<Bn * NHEAD * NCHUNK, 448, 0, stream>>>(Qw, Kw, Vw, offs, Ops,
                                                       Mlp, Bn);
  combine_kernel<<<Bn * ((NQ + CQ - 1) / CQ), 256, 0, stream>>>(
      Ops, Mlp, query, Wo, bo, out, Bn, NQ);
}